// Round 12
// baseline (376.315 us; speedup 1.0000x reference)
//
#include <hip/hip_runtime.h>

#define HIDDEN 128
#define SCAN_B 1024

typedef float v2f __attribute__((ext_vector_type(2)));
__device__ __forceinline__ v2f v2s(float a) { v2f r; r.x = a; r.y = a; return r; }

// ================= CSR build (per call; no fp atomics anywhere) =============
__global__ __launch_bounds__(256)
void k_hist(const int* __restrict__ dst, int* __restrict__ cnt,
            int* __restrict__ rank, int E) {
    int e = blockIdx.x * 256 + threadIdx.x;
    if (e < E) rank[e] = atomicAdd(&cnt[dst[e]], 1);
}

__global__ __launch_bounds__(SCAN_B)
void k_scan1(const int* __restrict__ cnt, int* __restrict__ offs,
             int* __restrict__ bsum, int N) {
    __shared__ int sm[SCAN_B];
    int g = blockIdx.x * SCAN_B + threadIdx.x;
    int v = (g < N) ? cnt[g] : 0;
    int acc = v;
    sm[threadIdx.x] = v;
    __syncthreads();
    for (int d = 1; d < SCAN_B; d <<= 1) {
        int t = (threadIdx.x >= d) ? sm[threadIdx.x - d] : 0;
        __syncthreads();
        acc += t;
        sm[threadIdx.x] = acc;
        __syncthreads();
    }
    if (g < N) offs[g] = acc - v;                 // exclusive
    if (threadIdx.x == SCAN_B - 1) bsum[blockIdx.x] = acc;
}

__global__ __launch_bounds__(SCAN_B)
void k_scan2(int* __restrict__ bsum, int nb) {
    __shared__ int sm[SCAN_B];
    int v = (threadIdx.x < nb) ? bsum[threadIdx.x] : 0;
    int acc = v;
    sm[threadIdx.x] = v;
    __syncthreads();
    for (int d = 1; d < SCAN_B; d <<= 1) {
        int t = (threadIdx.x >= d) ? sm[threadIdx.x - d] : 0;
        __syncthreads();
        acc += t;
        sm[threadIdx.x] = acc;
        __syncthreads();
    }
    if (threadIdx.x < nb) bsum[threadIdx.x] = acc - v;   // exclusive
}

__global__ __launch_bounds__(SCAN_B)
void k_scan3(int* __restrict__ offs, const int* __restrict__ bsum, int N) {
    int g = blockIdx.x * SCAN_B + threadIdx.x;
    if (g < N) offs[g] += bsum[blockIdx.x];
}

// Scatter edges into CSR order. One 8B packed store per edge (src, w).
__global__ __launch_bounds__(256)
void k_fill(const int* __restrict__ src, const int* __restrict__ dst,
            const float* __restrict__ ew, const int* __restrict__ offs,
            const int* __restrict__ rank, int2* __restrict__ cpack, int E) {
    int e = blockIdx.x * 256 + threadIdx.x;
    if (e >= E) return;
    int d = dst[e];
    int slot = offs[d] + rank[e];
    int2 p;
    p.x = src[e];
    p.y = __float_as_int(ew[e]);
    cpack[slot] = p;
}

__device__ __forceinline__ int end_of(const int* offs, int i, int N, int E) {
    return (i + 1 < N) ? offs[i + 1] : E;
}

// ================= layer 1: gather 2ch, emit combined y = (a0,a1,x0,x1) ====
__global__ __launch_bounds__(256)
void k_gather2(const int* __restrict__ offs, const int2* __restrict__ cpack,
               const float* __restrict__ x, float4* __restrict__ yv,
               int N, int E) {
    int i = blockIdx.x * 256 + threadIdx.x;
    if (i >= N) return;
    int start = offs[i], end = end_of(offs, i, N, E);
    float a0 = 0.f, a1 = 0.f;
    for (int j = start; j < end; ++j) {
        int2  p = cpack[j];
        int   s = p.x;
        float w = __int_as_float(p.y);
        float2 xv = *reinterpret_cast<const float2*>(x + (size_t)s * 2);
        a0 = fmaf(w, xv.x, a0);
        a1 = fmaf(w, xv.y, a1);
    }
    float2 xi = *reinterpret_cast<const float2*>(x + (size_t)i * 2);
    yv[i] = make_float4(a0, a1, xi.x, xi.y);
}

// ================= fused layer-2 aggregation + layer-1 node update ==========
// (R8 structure — per-lane staging + shfl + 8/4/1 cascade + packed v2f math)
#define EDGE4(sK, wK)                                              \
    {                                                              \
        v2f t = B + v2s((sK).x) * WR0 + v2s((sK).y) * WR1          \
                  + v2s((sK).z) * WO0 + v2s((sK).w) * WO1;         \
        t = __builtin_elementwise_max(t, Z);                       \
        acc = acc + v2s(wK) * t;                                   \
    }

__global__ __launch_bounds__(256)
void k_gatherfused(const int* __restrict__ offs, const int2* __restrict__ cpack,
                   const float4* __restrict__ yv,
                   const float* __restrict__ W1rel, const float* __restrict__ b1,
                   const float* __restrict__ W1root,
                   float* __restrict__ h, float* __restrict__ aggr,
                   int N, int E) {
    int wv   = (blockIdx.x * 256 + threadIdx.x) >> 6;
    int lane = threadIdx.x & 63;
    if (wv >= N) return;

    const int c0 = lane * 2;
    const v2f WR0 = *reinterpret_cast<const v2f*>(W1rel  + c0);
    const v2f WR1 = *reinterpret_cast<const v2f*>(W1rel  + HIDDEN + c0);
    const v2f WO0 = *reinterpret_cast<const v2f*>(W1root + c0);
    const v2f WO1 = *reinterpret_cast<const v2f*>(W1root + HIDDEN + c0);
    const v2f B   = *reinterpret_cast<const v2f*>(b1 + c0);
    const v2f Z   = {0.f, 0.f};

    int start = offs[wv], end = end_of(offs, wv, N, E);
    v2f acc = {0.f, 0.f};

    for (int base = start; base < end; base += 64) {
        int nb = min(64, end - base);
        int sx = 0, wb = 0;
        if (lane < nb) {                       // one coalesced 8B/lane load
            int2 p = cpack[base + lane];
            sx = p.x; wb = p.y;
        }
        int k = 0;
        for (; k + 8 <= nb; k += 8) {          // 8 loads in flight
            int s0 = __shfl(sx, k),     s1 = __shfl(sx, k + 1);
            int s2 = __shfl(sx, k + 2), s3 = __shfl(sx, k + 3);
            int s4 = __shfl(sx, k + 4), s5 = __shfl(sx, k + 5);
            int s6 = __shfl(sx, k + 6), s7 = __shfl(sx, k + 7);
            float w0 = __int_as_float(__shfl(wb, k));
            float w1 = __int_as_float(__shfl(wb, k + 1));
            float w2 = __int_as_float(__shfl(wb, k + 2));
            float w3 = __int_as_float(__shfl(wb, k + 3));
            float w4 = __int_as_float(__shfl(wb, k + 4));
            float w5 = __int_as_float(__shfl(wb, k + 5));
            float w6 = __int_as_float(__shfl(wb, k + 6));
            float w7 = __int_as_float(__shfl(wb, k + 7));
            float4 y0 = yv[s0]; float4 y1 = yv[s1];
            float4 y2 = yv[s2]; float4 y3 = yv[s3];
            float4 y4 = yv[s4]; float4 y5 = yv[s5];
            float4 y6 = yv[s6]; float4 y7 = yv[s7];
            EDGE4(y0, w0) EDGE4(y1, w1) EDGE4(y2, w2) EDGE4(y3, w3)
            EDGE4(y4, w4) EDGE4(y5, w5) EDGE4(y6, w6) EDGE4(y7, w7)
        }
        for (; k + 4 <= nb; k += 4) {          // 4-deep middle tier
            int s0 = __shfl(sx, k),     s1 = __shfl(sx, k + 1);
            int s2 = __shfl(sx, k + 2), s3 = __shfl(sx, k + 3);
            float w0 = __int_as_float(__shfl(wb, k));
            float w1 = __int_as_float(__shfl(wb, k + 1));
            float w2 = __int_as_float(__shfl(wb, k + 2));
            float w3 = __int_as_float(__shfl(wb, k + 3));
            float4 y0 = yv[s0]; float4 y1 = yv[s1];
            float4 y2 = yv[s2]; float4 y3 = yv[s3];
            EDGE4(y0, w0) EDGE4(y1, w1) EDGE4(y2, w2) EDGE4(y3, w3)
        }
        for (; k < nb; ++k) {                  // scalar tail (<=3)
            int   s0 = __shfl(sx, k);
            float w0 = __int_as_float(__shfl(wb, k));
            float4 y0 = yv[s0];
            EDGE4(y0, w0)
        }
    }

    *reinterpret_cast<v2f*>(aggr + (size_t)wv * HIDDEN + c0) = acc;

    // fused k_node1: this wave's own h1 row
    {
        float4 y = yv[wv];
        v2f t = B + v2s(y.x) * WR0 + v2s(y.y) * WR1
                  + v2s(y.z) * WO0 + v2s(y.w) * WO1;
        t = __builtin_elementwise_max(t, Z);
        *reinterpret_cast<v2f*>(h + (size_t)wv * HIDDEN + c0) = t;
    }
}

// ============ fused layer-2 node update + layer-3 projection ================
// R12: BM=64 grid (1563 blocks = 6.1 blocks/CU of WORK) + R11's tiny-LDS
// structure (X-only staging at BK=32, W from L2, W3s in LDS): 11.8KB/block.
// R6-R11 nulls unified: k_node2 was always wave-starved — BM=128 grids give
// only 782 blocks (3/CU exists => <=37% occupancy ceiling); BM=64+Ws-LDS
// capped residency at 2 blocks/CU. This config allows ~5 blocks/CU resident
// (VGPR-bound) with 6.1 available => ~60% occupancy, 3-4x every prior run.
// h2 = relu([aggr | h] @ [W2rel ; W2root] + b2)   (registers only)
// z  = h2 @ W3rel ; out = h2 @ W3root + b3        (h, aggr strictly read-only)
#define BM2 64
#define W3_STRIDE 7
#define XSW32(row, col) ((row) * 32 + ((col) ^ (((row) & 7) << 2)))

__global__ __launch_bounds__(256)
void k_node2(const float* __restrict__ aggr, const float* __restrict__ h,
             const float* __restrict__ Wrel, const float* __restrict__ b,
             const float* __restrict__ Wroot,
             const float* __restrict__ W3rel, const float* __restrict__ b3,
             const float* __restrict__ W3root,
             float* __restrict__ z, float* __restrict__ out, int N) {
    __shared__ float Xs[BM2 * 32];            // 64 x 32 swizzled, 8.2KB
    __shared__ float W3s[HIDDEN * W3_STRIDE]; // 3.6KB   => total 11.8KB

    const int tid = threadIdx.x;
    const int ci  = tid & 15;                 // channel group: cols ci*4, 64+ci*4
    const int ri  = tid >> 4;                 // node group: rows ri*4 .. ri*4+3
    const int nb  = blockIdx.x * BM2;

    // preload W3 (tiny, once) — ordered by the first __syncthreads below
    if (tid < HIDDEN) {
#pragma unroll
        for (int c = 0; c < 3; ++c) {
            W3s[tid * W3_STRIDE + c]     = W3rel [tid * 3 + c];
            W3s[tid * W3_STRIDE + 3 + c] = W3root[tid * 3 + c];
        }
    }

    float acc[4][8];
    {
        float4 b0 = *reinterpret_cast<const float4*>(b + ci * 4);
        float4 b1 = *reinterpret_cast<const float4*>(b + 64 + ci * 4);
#pragma unroll
        for (int m = 0; m < 4; ++m) {
            acc[m][0] = b0.x; acc[m][1] = b0.y; acc[m][2] = b0.z; acc[m][3] = b0.w;
            acc[m][4] = b1.x; acc[m][5] = b1.y; acc[m][6] = b1.z; acc[m][7] = b1.w;
        }
    }

    // K = 256 total: 8 tiles of BK=32. t<4: aggr @ Wrel; t>=4: h @ Wroot.
    for (int t = 0; t < 8; ++t) {
        const float* Xsrc = (t < 4) ? aggr : h;
        const float* Wsrc = (t < 4) ? Wrel : Wroot;
        const int kc = (t & 3) * 32;

        __syncthreads();                      // previous compute done before overwrite
        // stage X tile only: 64 rows x 32 cols, 2 float4/thread
#pragma unroll
        for (int q = 0; q < 2; ++q) {
            int idx = q * 256 + tid;          // 0..511
            int row = idx >> 3;
            int c4  = (idx & 7) * 4;
            int gr  = nb + row; if (gr >= N) gr = N - 1;
            float4 v = *reinterpret_cast<const float4*>(Xsrc + (size_t)gr * HIDDEN + kc + c4);
            *reinterpret_cast<float4*>(&Xs[XSW32(row, c4)]) = v;
        }
        __syncthreads();

        // compute: 32 k-steps, unrolled by 4; W rows straight from L2
#pragma unroll
        for (int kk = 0; kk < 32; kk += 4) {
            float4 xr[4];
#pragma unroll
            for (int m = 0; m < 4; ++m)
                xr[m] = *reinterpret_cast<const float4*>(&Xs[XSW32(ri * 4 + m, kk)]);
#pragma unroll
            for (int j = 0; j < 4; ++j) {
                const float* wrow = Wsrc + (size_t)(kc + kk + j) * HIDDEN;
                float4 w0 = *reinterpret_cast<const float4*>(wrow + ci * 4);
                float4 w1 = *reinterpret_cast<const float4*>(wrow + 64 + ci * 4);
#pragma unroll
                for (int m = 0; m < 4; ++m) {
                    float xm = (j == 0) ? xr[m].x : (j == 1) ? xr[m].y
                             : (j == 2) ? xr[m].z : xr[m].w;
                    acc[m][0] = fmaf(xm, w0.x, acc[m][0]);
                    acc[m][1] = fmaf(xm, w0.y, acc[m][1]);
                    acc[m][2] = fmaf(xm, w0.z, acc[m][2]);
                    acc[m][3] = fmaf(xm, w0.w, acc[m][3]);
                    acc[m][4] = fmaf(xm, w1.x, acc[m][4]);
                    acc[m][5] = fmaf(xm, w1.y, acc[m][5]);
                    acc[m][6] = fmaf(xm, w1.z, acc[m][6]);
                    acc[m][7] = fmaf(xm, w1.w, acc[m][7]);
                }
            }
        }
    }

    // epilogue: relu -> per-thread rank-8 partials vs LDS W3 -> width-16 shfl
    // reduce over the 16 ci-threads of each node -> z / out (h2 never stored)
    const float b30 = b3[0], b31 = b3[1], b32 = b3[2];
#pragma unroll
    for (int m = 0; m < 4; ++m) {
        int node = nb + ri * 4 + m;
        float zr0 = 0.f, zr1 = 0.f, zr2 = 0.f;
        float zo0 = 0.f, zo1 = 0.f, zo2 = 0.f;
#pragma unroll
        for (int jj = 0; jj < 4; ++jj) {
            float hv = fmaxf(acc[m][jj], 0.f);
            const float* w3 = &W3s[(ci * 4 + jj) * W3_STRIDE];
            zr0 = fmaf(hv, w3[0], zr0); zr1 = fmaf(hv, w3[1], zr1); zr2 = fmaf(hv, w3[2], zr2);
            zo0 = fmaf(hv, w3[3], zo0); zo1 = fmaf(hv, w3[4], zo1); zo2 = fmaf(hv, w3[5], zo2);
        }
#pragma unroll
        for (int jj = 0; jj < 4; ++jj) {
            float hv = fmaxf(acc[m][4 + jj], 0.f);
            const float* w3 = &W3s[(64 + ci * 4 + jj) * W3_STRIDE];
            zr0 = fmaf(hv, w3[0], zr0); zr1 = fmaf(hv, w3[1], zr1); zr2 = fmaf(hv, w3[2], zr2);
            zo0 = fmaf(hv, w3[3], zo0); zo1 = fmaf(hv, w3[4], zo1); zo2 = fmaf(hv, w3[5], zo2);
        }
#pragma unroll
        for (int d = 8; d >= 1; d >>= 1) {
            zr0 += __shfl_down(zr0, d, 16);
            zr1 += __shfl_down(zr1, d, 16);
            zr2 += __shfl_down(zr2, d, 16);
            zo0 += __shfl_down(zo0, d, 16);
            zo1 += __shfl_down(zo1, d, 16);
            zo2 += __shfl_down(zo2, d, 16);
        }
        if (ci == 0 && node < N) {
            z[(size_t)node * 3 + 0] = zr0;
            z[(size_t)node * 3 + 1] = zr1;
            z[(size_t)node * 3 + 2] = zr2;
            out[(size_t)node * 3 + 0] = zo0 + b30;
            out[(size_t)node * 3 + 1] = zo1 + b31;
            out[(size_t)node * 3 + 2] = zo2 + b32;
        }
    }
}

// ================= layer 3 gather =====================
__global__ __launch_bounds__(256)
void k_gather3(const int* __restrict__ offs, const int2* __restrict__ cpack,
               const float* __restrict__ z, float* __restrict__ out,
               int N, int E) {
    int i = blockIdx.x * 256 + threadIdx.x;
    if (i >= N) return;
    int start = offs[i], end = end_of(offs, i, N, E);
    float a0 = 0.f, a1 = 0.f, a2 = 0.f;
    for (int j = start; j < end; ++j) {
        int2  p = cpack[j];
        int   s = p.x;
        float w = __int_as_float(p.y);
        const float* zp = z + (size_t)s * 3;
        a0 = fmaf(w, zp[0], a0);
        a1 = fmaf(w, zp[1], a1);
        a2 = fmaf(w, zp[2], a2);
    }
    out[(size_t)i * 3 + 0] += a0;
    out[(size_t)i * 3 + 1] += a1;
    out[(size_t)i * 3 + 2] += a2;
}

extern "C" void kernel_launch(void* const* d_in, const int* in_sizes, int n_in,
                              void* d_out, int out_size, void* d_ws, size_t ws_size,
                              hipStream_t stream) {
    const float* x      = (const float*)d_in[0];
    const int*   ei     = (const int*)  d_in[1];
    const float* ew     = (const float*)d_in[2];
    const float* W1rel  = (const float*)d_in[4];
    const float* b1     = (const float*)d_in[5];
    const float* W1root = (const float*)d_in[6];
    const float* W2rel  = (const float*)d_in[7];
    const float* b2     = (const float*)d_in[8];
    const float* W2root = (const float*)d_in[9];
    const float* W3rel  = (const float*)d_in[10];
    const float* b3     = (const float*)d_in[11];
    const float* W3root = (const float*)d_in[12];
    float* out = (float*)d_out;

    const int N = in_sizes[0] / 2;
    const int E = in_sizes[2];
    const int* src = ei;
    const int* dst = ei + E;

    // -------- workspace layout --------
    // h     : N*128 f32   (h1; front E ints alias rank during CSR build)
    // aggr  : N*128 f32   (layer-2 aggregation; read-only in node2)
    // offs  : N int | bsum : SCAN_B int
    // cpack : E int2      (front N ints alias cnt — cnt dead before k_fill)
    // yv    : N float4    (combined (aggr1,x); dead after gatherfused —
    //         front N*3 f32 reused as z by node2/gather3)
    float* h    = (float*)d_ws;
    float* aggr = h + (size_t)N * HIDDEN;
    int*   offs = (int*)(aggr + (size_t)N * HIDDEN);
    int*   bsum = offs + N;
    size_t cpo  = (size_t)(bsum + SCAN_B - (int*)d_ws);
    cpo = (cpo + 1) & ~(size_t)1;          // 8B alignment
    int2*   cpack = (int2*)((int*)d_ws + cpo);
    size_t yvo  = (size_t)((char*)(cpack + E) - (char*)d_ws);
    yvo = (yvo + 15) & ~(size_t)15;        // 16B alignment
    float4* yv  = (float4*)((char*)d_ws + yvo);
    int* cnt  = (int*)cpack;               // alias: dead before k_fill writes cpack
    int* rank = (int*)h;                   // alias: dead before gatherfused writes h
    float* z  = (float*)yv;                // alias: yv dead after gatherfused

    const int nbScan = (N + SCAN_B - 1) / SCAN_B;

    // -------- CSR build --------
    hipMemsetAsync(cnt, 0, (size_t)N * sizeof(int), stream);
    k_hist <<<(E + 255) / 256, 256, 0, stream>>>(dst, cnt, rank, E);
    k_scan1<<<nbScan, SCAN_B, 0, stream>>>(cnt, offs, bsum, N);
    k_scan2<<<1, SCAN_B, 0, stream>>>(bsum, nbScan);
    k_scan3<<<nbScan, SCAN_B, 0, stream>>>(offs, bsum, N);
    k_fill <<<(E + 255) / 256, 256, 0, stream>>>(src, dst, ew, offs, rank, cpack, E);

    // -------- layer 1 aggregation (2ch) + y pack --------
    k_gather2<<<(N + 255) / 256, 256, 0, stream>>>(offs, cpack, x, yv, N, E);

    // -------- fused layer-2 aggregation + layer-1 node update --------
    {
        long long threads = (long long)N * 64;
        k_gatherfused<<<(int)((threads + 255) / 256), 256, 0, stream>>>(
            offs, cpack, yv, W1rel, b1, W1root, h, aggr, N, E);
    }

    // -------- fused layer-2 node update + layer-3 projection --------
    k_node2<<<(N + BM2 - 1) / BM2, 256, 0, stream>>>(
        aggr, h, W2rel, b2, W2root, W3rel, b3, W3root, z, out, N);

    // -------- layer 3 gather --------
    k_gather3<<<(N + 255) / 256, 256, 0, stream>>>(offs, cpack, z, out, N, E);
}

// Round 13
// 315.082 us; speedup vs baseline: 1.1943x; 1.1943x over previous
//
#include <hip/hip_runtime.h>

#define HIDDEN 128
#define SCAN_B 1024

typedef float v2f __attribute__((ext_vector_type(2)));
__device__ __forceinline__ v2f v2s(float a) { v2f r; r.x = a; r.y = a; return r; }

// ================= CSR build (per call; no fp atomics anywhere) =============
__global__ __launch_bounds__(256)
void k_hist(const int* __restrict__ dst, int* __restrict__ cnt,
            int* __restrict__ rank, int E) {
    int e = blockIdx.x * 256 + threadIdx.x;
    if (e < E) rank[e] = atomicAdd(&cnt[dst[e]], 1);
}

__global__ __launch_bounds__(SCAN_B)
void k_scan1(const int* __restrict__ cnt, int* __restrict__ offs,
             int* __restrict__ bsum, int N) {
    __shared__ int sm[SCAN_B];
    int g = blockIdx.x * SCAN_B + threadIdx.x;
    int v = (g < N) ? cnt[g] : 0;
    int acc = v;
    sm[threadIdx.x] = v;
    __syncthreads();
    for (int d = 1; d < SCAN_B; d <<= 1) {
        int t = (threadIdx.x >= d) ? sm[threadIdx.x - d] : 0;
        __syncthreads();
        acc += t;
        sm[threadIdx.x] = acc;
        __syncthreads();
    }
    if (g < N) offs[g] = acc - v;                 // exclusive
    if (threadIdx.x == SCAN_B - 1) bsum[blockIdx.x] = acc;
}

__global__ __launch_bounds__(SCAN_B)
void k_scan2(int* __restrict__ bsum, int nb) {
    __shared__ int sm[SCAN_B];
    int v = (threadIdx.x < nb) ? bsum[threadIdx.x] : 0;
    int acc = v;
    sm[threadIdx.x] = v;
    __syncthreads();
    for (int d = 1; d < SCAN_B; d <<= 1) {
        int t = (threadIdx.x >= d) ? sm[threadIdx.x - d] : 0;
        __syncthreads();
        acc += t;
        sm[threadIdx.x] = acc;
        __syncthreads();
    }
    if (threadIdx.x < nb) bsum[threadIdx.x] = acc - v;   // exclusive
}

__global__ __launch_bounds__(SCAN_B)
void k_scan3(int* __restrict__ offs, const int* __restrict__ bsum, int N) {
    int g = blockIdx.x * SCAN_B + threadIdx.x;
    if (g < N) offs[g] += bsum[blockIdx.x];
}

// Scatter edges into CSR order. One 8B packed store per edge (src, w).
__global__ __launch_bounds__(256)
void k_fill(const int* __restrict__ src, const int* __restrict__ dst,
            const float* __restrict__ ew, const int* __restrict__ offs,
            const int* __restrict__ rank, int2* __restrict__ cpack, int E) {
    int e = blockIdx.x * 256 + threadIdx.x;
    if (e >= E) return;
    int d = dst[e];
    int slot = offs[d] + rank[e];
    int2 p;
    p.x = src[e];
    p.y = __float_as_int(ew[e]);
    cpack[slot] = p;
}

__device__ __forceinline__ int end_of(const int* offs, int i, int N, int E) {
    return (i + 1 < N) ? offs[i + 1] : E;
}

// ================= layer 1: gather 2ch, emit combined y = (a0,a1,x0,x1) ====
__global__ __launch_bounds__(256)
void k_gather2(const int* __restrict__ offs, const int2* __restrict__ cpack,
               const float* __restrict__ x, float4* __restrict__ yv,
               int N, int E) {
    int i = blockIdx.x * 256 + threadIdx.x;
    if (i >= N) return;
    int start = offs[i], end = end_of(offs, i, N, E);
    float a0 = 0.f, a1 = 0.f;
    for (int j = start; j < end; ++j) {
        int2  p = cpack[j];
        int   s = p.x;
        float w = __int_as_float(p.y);
        float2 xv = *reinterpret_cast<const float2*>(x + (size_t)s * 2);
        a0 = fmaf(w, xv.x, a0);
        a1 = fmaf(w, xv.y, a1);
    }
    float2 xi = *reinterpret_cast<const float2*>(x + (size_t)i * 2);
    yv[i] = make_float4(a0, a1, xi.x, xi.y);
}

// ================= fused layer-2 aggregation + layer-1 node update ==========
// (R8 structure — per-lane staging + shfl + 8/4/1 cascade + packed v2f math)
#define EDGE4(sK, wK)                                              \
    {                                                              \
        v2f t = B + v2s((sK).x) * WR0 + v2s((sK).y) * WR1          \
                  + v2s((sK).z) * WO0 + v2s((sK).w) * WO1;         \
        t = __builtin_elementwise_max(t, Z);                       \
        acc = acc + v2s(wK) * t;                                   \
    }

__global__ __launch_bounds__(256)
void k_gatherfused(const int* __restrict__ offs, const int2* __restrict__ cpack,
                   const float4* __restrict__ yv,
                   const float* __restrict__ W1rel, const float* __restrict__ b1,
                   const float* __restrict__ W1root,
                   float* __restrict__ h, float* __restrict__ aggr,
                   int N, int E) {
    int wv   = (blockIdx.x * 256 + threadIdx.x) >> 6;
    int lane = threadIdx.x & 63;
    if (wv >= N) return;

    const int c0 = lane * 2;
    const v2f WR0 = *reinterpret_cast<const v2f*>(W1rel  + c0);
    const v2f WR1 = *reinterpret_cast<const v2f*>(W1rel  + HIDDEN + c0);
    const v2f WO0 = *reinterpret_cast<const v2f*>(W1root + c0);
    const v2f WO1 = *reinterpret_cast<const v2f*>(W1root + HIDDEN + c0);
    const v2f B   = *reinterpret_cast<const v2f*>(b1 + c0);
    const v2f Z   = {0.f, 0.f};

    int start = offs[wv], end = end_of(offs, wv, N, E);
    v2f acc = {0.f, 0.f};

    for (int base = start; base < end; base += 64) {
        int nb = min(64, end - base);
        int sx = 0, wb = 0;
        if (lane < nb) {                       // one coalesced 8B/lane load
            int2 p = cpack[base + lane];
            sx = p.x; wb = p.y;
        }
        int k = 0;
        for (; k + 8 <= nb; k += 8) {          // 8 loads in flight
            int s0 = __shfl(sx, k),     s1 = __shfl(sx, k + 1);
            int s2 = __shfl(sx, k + 2), s3 = __shfl(sx, k + 3);
            int s4 = __shfl(sx, k + 4), s5 = __shfl(sx, k + 5);
            int s6 = __shfl(sx, k + 6), s7 = __shfl(sx, k + 7);
            float w0 = __int_as_float(__shfl(wb, k));
            float w1 = __int_as_float(__shfl(wb, k + 1));
            float w2 = __int_as_float(__shfl(wb, k + 2));
            float w3 = __int_as_float(__shfl(wb, k + 3));
            float w4 = __int_as_float(__shfl(wb, k + 4));
            float w5 = __int_as_float(__shfl(wb, k + 5));
            float w6 = __int_as_float(__shfl(wb, k + 6));
            float w7 = __int_as_float(__shfl(wb, k + 7));
            float4 y0 = yv[s0]; float4 y1 = yv[s1];
            float4 y2 = yv[s2]; float4 y3 = yv[s3];
            float4 y4 = yv[s4]; float4 y5 = yv[s5];
            float4 y6 = yv[s6]; float4 y7 = yv[s7];
            EDGE4(y0, w0) EDGE4(y1, w1) EDGE4(y2, w2) EDGE4(y3, w3)
            EDGE4(y4, w4) EDGE4(y5, w5) EDGE4(y6, w6) EDGE4(y7, w7)
        }
        for (; k + 4 <= nb; k += 4) {          // 4-deep middle tier
            int s0 = __shfl(sx, k),     s1 = __shfl(sx, k + 1);
            int s2 = __shfl(sx, k + 2), s3 = __shfl(sx, k + 3);
            float w0 = __int_as_float(__shfl(wb, k));
            float w1 = __int_as_float(__shfl(wb, k + 1));
            float w2 = __int_as_float(__shfl(wb, k + 2));
            float w3 = __int_as_float(__shfl(wb, k + 3));
            float4 y0 = yv[s0]; float4 y1 = yv[s1];
            float4 y2 = yv[s2]; float4 y3 = yv[s3];
            EDGE4(y0, w0) EDGE4(y1, w1) EDGE4(y2, w2) EDGE4(y3, w3)
        }
        for (; k < nb; ++k) {                  // scalar tail (<=3)
            int   s0 = __shfl(sx, k);
            float w0 = __int_as_float(__shfl(wb, k));
            float4 y0 = yv[s0];
            EDGE4(y0, w0)
        }
    }

    *reinterpret_cast<v2f*>(aggr + (size_t)wv * HIDDEN + c0) = acc;

    // fused k_node1: this wave's own h1 row
    {
        float4 y = yv[wv];
        v2f t = B + v2s(y.x) * WR0 + v2s(y.y) * WR1
                  + v2s(y.z) * WO0 + v2s(y.w) * WO1;
        t = __builtin_elementwise_max(t, Z);
        *reinterpret_cast<v2f*>(h + (size_t)wv * HIDDEN + c0) = t;
    }
}

// ============ fused layer-2 node update + layer-3 projection ================
// R13: the CLEAN occupancy experiment. R8's exact proven structure (BM=64,
// W in LDS — 110us at 2 blocks/CU) with BK=32: LDS = Xs 8.2 + Ws 16.4 +
// W3s 3.6 = 28.2KB -> 4 blocks/CU under the measured ~128KB pool, 2x R8's
// residency, with an UNCHANGED instruction mix (same ds_read count, same
// W staging; R10 showed 8 phases ~ 4 phases). R12's regression was a
// confound: W-from-global at BM=64 doubled W-load rate and VGPR-60 codegen
// serialized it — not an occupancy result.
// h2 = relu([aggr | h] @ [W2rel ; W2root] + b2)   (registers only)
// z  = h2 @ W3rel ; out = h2 @ W3root + b3        (h, aggr strictly read-only)
#define BM2 64
#define W3_STRIDE 7
#define XSW32(row, col) ((row) * 32 + ((col) ^ (((row) & 7) << 2)))

__global__ __launch_bounds__(256)
void k_node2(const float* __restrict__ aggr, const float* __restrict__ h,
             const float* __restrict__ Wrel, const float* __restrict__ b,
             const float* __restrict__ Wroot,
             const float* __restrict__ W3rel, const float* __restrict__ b3,
             const float* __restrict__ W3root,
             float* __restrict__ z, float* __restrict__ out, int N) {
    __shared__ float Xs[BM2 * 32];            // 64 x 32 swizzled, 8.2KB
    __shared__ float Ws[32 * HIDDEN];         // 32 x 128 weight tile, 16.4KB
    __shared__ float W3s[HIDDEN * W3_STRIDE]; // 3.6KB   => total 28.2KB

    const int tid = threadIdx.x;
    const int ci  = tid & 15;                 // channel group: cols ci*4, 64+ci*4
    const int ri  = tid >> 4;                 // node group: rows ri*4 .. ri*4+3
    const int nb  = blockIdx.x * BM2;

    // preload W3 (tiny, once) — ordered by the first __syncthreads below
    if (tid < HIDDEN) {
#pragma unroll
        for (int c = 0; c < 3; ++c) {
            W3s[tid * W3_STRIDE + c]     = W3rel [tid * 3 + c];
            W3s[tid * W3_STRIDE + 3 + c] = W3root[tid * 3 + c];
        }
    }

    float acc[4][8];
    {
        float4 b0 = *reinterpret_cast<const float4*>(b + ci * 4);
        float4 b1 = *reinterpret_cast<const float4*>(b + 64 + ci * 4);
#pragma unroll
        for (int m = 0; m < 4; ++m) {
            acc[m][0] = b0.x; acc[m][1] = b0.y; acc[m][2] = b0.z; acc[m][3] = b0.w;
            acc[m][4] = b1.x; acc[m][5] = b1.y; acc[m][6] = b1.z; acc[m][7] = b1.w;
        }
    }

    // K = 256 total: 8 tiles of BK=32. t<4: aggr @ Wrel; t>=4: h @ Wroot.
    for (int t = 0; t < 8; ++t) {
        const float* Xsrc = (t < 4) ? aggr : h;
        const float* Wsrc = (t < 4) ? Wrel : Wroot;
        const int kc = (t & 3) * 32;

        __syncthreads();                      // previous compute done before overwrite
        // stage X tile: 64 rows x 32 cols, 2 float4/thread
#pragma unroll
        for (int q = 0; q < 2; ++q) {
            int idx = q * 256 + tid;          // 0..511
            int row = idx >> 3;
            int c4  = (idx & 7) * 4;
            int gr  = nb + row; if (gr >= N) gr = N - 1;
            float4 v = *reinterpret_cast<const float4*>(Xsrc + (size_t)gr * HIDDEN + kc + c4);
            *reinterpret_cast<float4*>(&Xs[XSW32(row, c4)]) = v;
        }
        // stage W tile: rows kc..kc+31 of [128][128], 4 float4/thread
#pragma unroll
        for (int q = 0; q < 4; ++q) {
            int idx = q * 256 + tid;          // 0..1023
            int row = idx >> 5;
            int c4  = (idx & 31) * 4;
            float4 v = *reinterpret_cast<const float4*>(Wsrc + (size_t)(kc + row) * HIDDEN + c4);
            *reinterpret_cast<float4*>(&Ws[row * HIDDEN + c4]) = v;
        }
        __syncthreads();

        // compute: 32 k-steps, unrolled by 4 with float4 LDS reads
#pragma unroll
        for (int kk = 0; kk < 32; kk += 4) {
            float4 xr[4];
#pragma unroll
            for (int m = 0; m < 4; ++m)
                xr[m] = *reinterpret_cast<const float4*>(&Xs[XSW32(ri * 4 + m, kk)]);
#pragma unroll
            for (int j = 0; j < 4; ++j) {
                float4 w0 = *reinterpret_cast<const float4*>(&Ws[(kk + j) * HIDDEN + ci * 4]);
                float4 w1 = *reinterpret_cast<const float4*>(&Ws[(kk + j) * HIDDEN + 64 + ci * 4]);
#pragma unroll
                for (int m = 0; m < 4; ++m) {
                    float xm = (j == 0) ? xr[m].x : (j == 1) ? xr[m].y
                             : (j == 2) ? xr[m].z : xr[m].w;
                    acc[m][0] = fmaf(xm, w0.x, acc[m][0]);
                    acc[m][1] = fmaf(xm, w0.y, acc[m][1]);
                    acc[m][2] = fmaf(xm, w0.z, acc[m][2]);
                    acc[m][3] = fmaf(xm, w0.w, acc[m][3]);
                    acc[m][4] = fmaf(xm, w1.x, acc[m][4]);
                    acc[m][5] = fmaf(xm, w1.y, acc[m][5]);
                    acc[m][6] = fmaf(xm, w1.z, acc[m][6]);
                    acc[m][7] = fmaf(xm, w1.w, acc[m][7]);
                }
            }
        }
    }

    // epilogue: relu -> per-thread rank-8 partials vs LDS W3 -> width-16 shfl
    // reduce over the 16 ci-threads of each node -> z / out (h2 never stored)
    const float b30 = b3[0], b31 = b3[1], b32 = b3[2];
#pragma unroll
    for (int m = 0; m < 4; ++m) {
        int node = nb + ri * 4 + m;
        float zr0 = 0.f, zr1 = 0.f, zr2 = 0.f;
        float zo0 = 0.f, zo1 = 0.f, zo2 = 0.f;
#pragma unroll
        for (int jj = 0; jj < 4; ++jj) {
            float hv = fmaxf(acc[m][jj], 0.f);
            const float* w3 = &W3s[(ci * 4 + jj) * W3_STRIDE];
            zr0 = fmaf(hv, w3[0], zr0); zr1 = fmaf(hv, w3[1], zr1); zr2 = fmaf(hv, w3[2], zr2);
            zo0 = fmaf(hv, w3[3], zo0); zo1 = fmaf(hv, w3[4], zo1); zo2 = fmaf(hv, w3[5], zo2);
        }
#pragma unroll
        for (int jj = 0; jj < 4; ++jj) {
            float hv = fmaxf(acc[m][4 + jj], 0.f);
            const float* w3 = &W3s[(64 + ci * 4 + jj) * W3_STRIDE];
            zr0 = fmaf(hv, w3[0], zr0); zr1 = fmaf(hv, w3[1], zr1); zr2 = fmaf(hv, w3[2], zr2);
            zo0 = fmaf(hv, w3[3], zo0); zo1 = fmaf(hv, w3[4], zo1); zo2 = fmaf(hv, w3[5], zo2);
        }
#pragma unroll
        for (int d = 8; d >= 1; d >>= 1) {
            zr0 += __shfl_down(zr0, d, 16);
            zr1 += __shfl_down(zr1, d, 16);
            zr2 += __shfl_down(zr2, d, 16);
            zo0 += __shfl_down(zo0, d, 16);
            zo1 += __shfl_down(zo1, d, 16);
            zo2 += __shfl_down(zo2, d, 16);
        }
        if (ci == 0 && node < N) {
            z[(size_t)node * 3 + 0] = zr0;
            z[(size_t)node * 3 + 1] = zr1;
            z[(size_t)node * 3 + 2] = zr2;
            out[(size_t)node * 3 + 0] = zo0 + b30;
            out[(size_t)node * 3 + 1] = zo1 + b31;
            out[(size_t)node * 3 + 2] = zo2 + b32;
        }
    }
}

// ================= layer 3 gather =====================
__global__ __launch_bounds__(256)
void k_gather3(const int* __restrict__ offs, const int2* __restrict__ cpack,
               const float* __restrict__ z, float* __restrict__ out,
               int N, int E) {
    int i = blockIdx.x * 256 + threadIdx.x;
    if (i >= N) return;
    int start = offs[i], end = end_of(offs, i, N, E);
    float a0 = 0.f, a1 = 0.f, a2 = 0.f;
    for (int j = start; j < end; ++j) {
        int2  p = cpack[j];
        int   s = p.x;
        float w = __int_as_float(p.y);
        const float* zp = z + (size_t)s * 3;
        a0 = fmaf(w, zp[0], a0);
        a1 = fmaf(w, zp[1], a1);
        a2 = fmaf(w, zp[2], a2);
    }
    out[(size_t)i * 3 + 0] += a0;
    out[(size_t)i * 3 + 1] += a1;
    out[(size_t)i * 3 + 2] += a2;
}

extern "C" void kernel_launch(void* const* d_in, const int* in_sizes, int n_in,
                              void* d_out, int out_size, void* d_ws, size_t ws_size,
                              hipStream_t stream) {
    const float* x      = (const float*)d_in[0];
    const int*   ei     = (const int*)  d_in[1];
    const float* ew     = (const float*)d_in[2];
    const float* W1rel  = (const float*)d_in[4];
    const float* b1     = (const float*)d_in[5];
    const float* W1root = (const float*)d_in[6];
    const float* W2rel  = (const float*)d_in[7];
    const float* b2     = (const float*)d_in[8];
    const float* W2root = (const float*)d_in[9];
    const float* W3rel  = (const float*)d_in[10];
    const float* b3     = (const float*)d_in[11];
    const float* W3root = (const float*)d_in[12];
    float* out = (float*)d_out;

    const int N = in_sizes[0] / 2;
    const int E = in_sizes[2];
    const int* src = ei;
    const int* dst = ei + E;

    // -------- workspace layout --------
    // h     : N*128 f32   (h1; front E ints alias rank during CSR build)
    // aggr  : N*128 f32   (layer-2 aggregation; read-only in node2)
    // offs  : N int | bsum : SCAN_B int
    // cpack : E int2      (front N ints alias cnt — cnt dead before k_fill)
    // yv    : N float4    (combined (aggr1,x); dead after gatherfused —
    //         front N*3 f32 reused as z by node2/gather3)
    float* h    = (float*)d_ws;
    float* aggr = h + (size_t)N * HIDDEN;
    int*   offs = (int*)(aggr + (size_t)N * HIDDEN);
    int*   bsum = offs + N;
    size_t cpo  = (size_t)(bsum + SCAN_B - (int*)d_ws);
    cpo = (cpo + 1) & ~(size_t)1;          // 8B alignment
    int2*   cpack = (int2*)((int*)d_ws + cpo);
    size_t yvo  = (size_t)((char*)(cpack + E) - (char*)d_ws);
    yvo = (yvo + 15) & ~(size_t)15;        // 16B alignment
    float4* yv  = (float4*)((char*)d_ws + yvo);
    int* cnt  = (int*)cpack;               // alias: dead before k_fill writes cpack
    int* rank = (int*)h;                   // alias: dead before gatherfused writes h
    float* z  = (float*)yv;                // alias: yv dead after gatherfused

    const int nbScan = (N + SCAN_B - 1) / SCAN_B;

    // -------- CSR build --------
    hipMemsetAsync(cnt, 0, (size_t)N * sizeof(int), stream);
    k_hist <<<(E + 255) / 256, 256, 0, stream>>>(dst, cnt, rank, E);
    k_scan1<<<nbScan, SCAN_B, 0, stream>>>(cnt, offs, bsum, N);
    k_scan2<<<1, SCAN_B, 0, stream>>>(bsum, nbScan);
    k_scan3<<<nbScan, SCAN_B, 0, stream>>>(offs, bsum, N);
    k_fill <<<(E + 255) / 256, 256, 0, stream>>>(src, dst, ew, offs, rank, cpack, E);

    // -------- layer 1 aggregation (2ch) + y pack --------
    k_gather2<<<(N + 255) / 256, 256, 0, stream>>>(offs, cpack, x, yv, N, E);

    // -------- fused layer-2 aggregation + layer-1 node update --------
    {
        long long threads = (long long)N * 64;
        k_gatherfused<<<(int)((threads + 255) / 256), 256, 0, stream>>>(
            offs, cpack, yv, W1rel, b1, W1root, h, aggr, N, E);
    }

    // -------- fused layer-2 node update + layer-3 projection --------
    k_node2<<<(N + BM2 - 1) / BM2, 256, 0, stream>>>(
        aggr, h, W2rel, b2, W2root, W3rel, b3, W3root, z, out, N);

    // -------- layer 3 gather --------
    k_gather3<<<(N + 255) / 256, 256, 0, stream>>>(offs, cpack, z, out, N, E);
}

// Round 14
// 280.467 us; speedup vs baseline: 1.3417x; 1.1234x over previous
//
#include <hip/hip_runtime.h>

#define HIDDEN 128
#define SCAN_B 1024

typedef float v2f __attribute__((ext_vector_type(2)));
typedef short short8 __attribute__((ext_vector_type(8)));
typedef float f32x4 __attribute__((ext_vector_type(4)));
__device__ __forceinline__ v2f v2s(float a) { v2f r; r.x = a; r.y = a; return r; }

// bf16 split helpers (RNE)
__device__ __forceinline__ ushort f2bf(float f) {
    uint u = __float_as_uint(f);
    u += 0x7FFFu + ((u >> 16) & 1u);
    return (ushort)(u >> 16);
}
__device__ __forceinline__ float bf2f(ushort h) {
    return __uint_as_float(((uint)h) << 16);
}

// ================= CSR build (per call; no fp atomics anywhere) =============
__global__ __launch_bounds__(256)
void k_hist(const int* __restrict__ dst, int* __restrict__ cnt,
            int* __restrict__ rank, int E) {
    int e = blockIdx.x * 256 + threadIdx.x;
    if (e < E) rank[e] = atomicAdd(&cnt[dst[e]], 1);
}

__global__ __launch_bounds__(SCAN_B)
void k_scan1(const int* __restrict__ cnt, int* __restrict__ offs,
             int* __restrict__ bsum, int N) {
    __shared__ int sm[SCAN_B];
    int g = blockIdx.x * SCAN_B + threadIdx.x;
    int v = (g < N) ? cnt[g] : 0;
    int acc = v;
    sm[threadIdx.x] = v;
    __syncthreads();
    for (int d = 1; d < SCAN_B; d <<= 1) {
        int t = (threadIdx.x >= d) ? sm[threadIdx.x - d] : 0;
        __syncthreads();
        acc += t;
        sm[threadIdx.x] = acc;
        __syncthreads();
    }
    if (g < N) offs[g] = acc - v;                 // exclusive
    if (threadIdx.x == SCAN_B - 1) bsum[blockIdx.x] = acc;
}

__global__ __launch_bounds__(SCAN_B)
void k_scan2(int* __restrict__ bsum, int nb) {
    __shared__ int sm[SCAN_B];
    int v = (threadIdx.x < nb) ? bsum[threadIdx.x] : 0;
    int acc = v;
    sm[threadIdx.x] = v;
    __syncthreads();
    for (int d = 1; d < SCAN_B; d <<= 1) {
        int t = (threadIdx.x >= d) ? sm[threadIdx.x - d] : 0;
        __syncthreads();
        acc += t;
        sm[threadIdx.x] = acc;
        __syncthreads();
    }
    if (threadIdx.x < nb) bsum[threadIdx.x] = acc - v;   // exclusive
}

__global__ __launch_bounds__(SCAN_B)
void k_scan3(int* __restrict__ offs, const int* __restrict__ bsum, int N) {
    int g = blockIdx.x * SCAN_B + threadIdx.x;
    if (g < N) offs[g] += bsum[blockIdx.x];
}

// Scatter edges into CSR order. One 8B packed store per edge (src, w).
__global__ __launch_bounds__(256)
void k_fill(const int* __restrict__ src, const int* __restrict__ dst,
            const float* __restrict__ ew, const int* __restrict__ offs,
            const int* __restrict__ rank, int2* __restrict__ cpack, int E) {
    int e = blockIdx.x * 256 + threadIdx.x;
    if (e >= E) return;
    int d = dst[e];
    int slot = offs[d] + rank[e];
    int2 p;
    p.x = src[e];
    p.y = __float_as_int(ew[e]);
    cpack[slot] = p;
}

__device__ __forceinline__ int end_of(const int* offs, int i, int N, int E) {
    return (i + 1 < N) ? offs[i + 1] : E;
}

// ================= layer 1: gather 2ch, emit combined y = (a0,a1,x0,x1) ====
__global__ __launch_bounds__(256)
void k_gather2(const int* __restrict__ offs, const int2* __restrict__ cpack,
               const float* __restrict__ x, float4* __restrict__ yv,
               int N, int E) {
    int i = blockIdx.x * 256 + threadIdx.x;
    if (i >= N) return;
    int start = offs[i], end = end_of(offs, i, N, E);
    float a0 = 0.f, a1 = 0.f;
    for (int j = start; j < end; ++j) {
        int2  p = cpack[j];
        int   s = p.x;
        float w = __int_as_float(p.y);
        float2 xv = *reinterpret_cast<const float2*>(x + (size_t)s * 2);
        a0 = fmaf(w, xv.x, a0);
        a1 = fmaf(w, xv.y, a1);
    }
    float2 xi = *reinterpret_cast<const float2*>(x + (size_t)i * 2);
    yv[i] = make_float4(a0, a1, xi.x, xi.y);
}

// ================= fused layer-2 aggregation + layer-1 node update ==========
// (R8 structure) — epilogue now emits bf16 hi/lo splits of aggr and h1 for
// the MFMA node2 (same byte count as the old fp32 stores).
#define EDGE4(sK, wK)                                              \
    {                                                              \
        v2f t = B + v2s((sK).x) * WR0 + v2s((sK).y) * WR1          \
                  + v2s((sK).z) * WO0 + v2s((sK).w) * WO1;         \
        t = __builtin_elementwise_max(t, Z);                       \
        acc = acc + v2s(wK) * t;                                   \
    }

__global__ __launch_bounds__(256)
void k_gatherfused(const int* __restrict__ offs, const int2* __restrict__ cpack,
                   const float4* __restrict__ yv,
                   const float* __restrict__ W1rel, const float* __restrict__ b1,
                   const float* __restrict__ W1root,
                   ushort* __restrict__ h_hi, ushort* __restrict__ h_lo,
                   ushort* __restrict__ a_hi, ushort* __restrict__ a_lo,
                   int N, int E) {
    int wv   = (blockIdx.x * 256 + threadIdx.x) >> 6;
    int lane = threadIdx.x & 63;
    if (wv >= N) return;

    const int c0 = lane * 2;
    const v2f WR0 = *reinterpret_cast<const v2f*>(W1rel  + c0);
    const v2f WR1 = *reinterpret_cast<const v2f*>(W1rel  + HIDDEN + c0);
    const v2f WO0 = *reinterpret_cast<const v2f*>(W1root + c0);
    const v2f WO1 = *reinterpret_cast<const v2f*>(W1root + HIDDEN + c0);
    const v2f B   = *reinterpret_cast<const v2f*>(b1 + c0);
    const v2f Z   = {0.f, 0.f};

    int start = offs[wv], end = end_of(offs, wv, N, E);
    v2f acc = {0.f, 0.f};

    for (int base = start; base < end; base += 64) {
        int nb = min(64, end - base);
        int sx = 0, wb = 0;
        if (lane < nb) {                       // one coalesced 8B/lane load
            int2 p = cpack[base + lane];
            sx = p.x; wb = p.y;
        }
        int k = 0;
        for (; k + 8 <= nb; k += 8) {          // 8 loads in flight
            int s0 = __shfl(sx, k),     s1 = __shfl(sx, k + 1);
            int s2 = __shfl(sx, k + 2), s3 = __shfl(sx, k + 3);
            int s4 = __shfl(sx, k + 4), s5 = __shfl(sx, k + 5);
            int s6 = __shfl(sx, k + 6), s7 = __shfl(sx, k + 7);
            float w0 = __int_as_float(__shfl(wb, k));
            float w1 = __int_as_float(__shfl(wb, k + 1));
            float w2 = __int_as_float(__shfl(wb, k + 2));
            float w3 = __int_as_float(__shfl(wb, k + 3));
            float w4 = __int_as_float(__shfl(wb, k + 4));
            float w5 = __int_as_float(__shfl(wb, k + 5));
            float w6 = __int_as_float(__shfl(wb, k + 6));
            float w7 = __int_as_float(__shfl(wb, k + 7));
            float4 y0 = yv[s0]; float4 y1 = yv[s1];
            float4 y2 = yv[s2]; float4 y3 = yv[s3];
            float4 y4 = yv[s4]; float4 y5 = yv[s5];
            float4 y6 = yv[s6]; float4 y7 = yv[s7];
            EDGE4(y0, w0) EDGE4(y1, w1) EDGE4(y2, w2) EDGE4(y3, w3)
            EDGE4(y4, w4) EDGE4(y5, w5) EDGE4(y6, w6) EDGE4(y7, w7)
        }
        for (; k + 4 <= nb; k += 4) {          // 4-deep middle tier
            int s0 = __shfl(sx, k),     s1 = __shfl(sx, k + 1);
            int s2 = __shfl(sx, k + 2), s3 = __shfl(sx, k + 3);
            float w0 = __int_as_float(__shfl(wb, k));
            float w1 = __int_as_float(__shfl(wb, k + 1));
            float w2 = __int_as_float(__shfl(wb, k + 2));
            float w3 = __int_as_float(__shfl(wb, k + 3));
            float4 y0 = yv[s0]; float4 y1 = yv[s1];
            float4 y2 = yv[s2]; float4 y3 = yv[s3];
            EDGE4(y0, w0) EDGE4(y1, w1) EDGE4(y2, w2) EDGE4(y3, w3)
        }
        for (; k < nb; ++k) {                  // scalar tail (<=3)
            int   s0 = __shfl(sx, k);
            float w0 = __int_as_float(__shfl(wb, k));
            float4 y0 = yv[s0];
            EDGE4(y0, w0)
        }
    }

    // aggr -> bf16 hi/lo
    {
        ushort hx = f2bf(acc.x);
        ushort lx = f2bf(acc.x - bf2f(hx));
        ushort hy = f2bf(acc.y);
        ushort ly = f2bf(acc.y - bf2f(hy));
        ushort2 hv2; hv2.x = hx; hv2.y = hy;
        ushort2 lv2; lv2.x = lx; lv2.y = ly;
        *reinterpret_cast<ushort2*>(a_hi + (size_t)wv * HIDDEN + c0) = hv2;
        *reinterpret_cast<ushort2*>(a_lo + (size_t)wv * HIDDEN + c0) = lv2;
    }

    // fused k_node1: this wave's own h1 row -> bf16 hi/lo
    {
        float4 y = yv[wv];
        v2f t = B + v2s(y.x) * WR0 + v2s(y.y) * WR1
                  + v2s(y.z) * WO0 + v2s(y.w) * WO1;
        t = __builtin_elementwise_max(t, Z);
        ushort hx = f2bf(t.x);
        ushort lx = f2bf(t.x - bf2f(hx));
        ushort hy = f2bf(t.y);
        ushort ly = f2bf(t.y - bf2f(hy));
        ushort2 hv2; hv2.x = hx; hv2.y = hy;
        ushort2 lv2; lv2.x = lx; lv2.y = ly;
        *reinterpret_cast<ushort2*>(h_hi + (size_t)wv * HIDDEN + c0) = hv2;
        *reinterpret_cast<ushort2*>(h_lo + (size_t)wv * HIDDEN + c0) = lv2;
    }
}

// ============ layer-2 node update on the MATRIX pipe + layer-3 fusion =======
// R14: k_node2 rebuilt on MFMA. R8-R13 model: fp32-VALU GEMM floor 42us +
// 94us LDS-read bill = the 107us plateau. bf16 2-term split (hi+lo, 3
// products hi*hi + hi*lo + lo*hi) has ~2^-16 rel error (<< absmax 0.03125)
// and runs on the 2.2PF matrix pipe: MFMA ~10us, LDS ~20us, HBM 16us.
// Geometry: 256 thr = 4 waves; wave = 16 rows x 128 cols via 8 col-tiles of
// mfma_f32_16x16x32_bf16 (acc 8 x f32x4). K = 256 in 8 phases of 32.
// X staged pre-split (from gatherfused); W split in-staging, transposed
// [n][k] bf16, 80B-padded rows (frag reads 2-way = free).
// Fragment layouts (per cdna4 docs): A row=l&15, B col=l&15, k=(l>>4)*8+i;
// D col=l&15, row=(l>>4)*4+reg (m89-verified) -> epilogue = R7's shfl-16.
#define BM2 64
#define W3_STRIDE 7
#define XS_LD 40   // ushorts per LDS row: 32 k + 8 pad (80B, 16B-aligned)

__global__ __launch_bounds__(256)
void k_node2(const ushort* __restrict__ a_hi, const ushort* __restrict__ a_lo,
             const ushort* __restrict__ h_hi, const ushort* __restrict__ h_lo,
             const float* __restrict__ Wrel, const float* __restrict__ b,
             const float* __restrict__ Wroot,
             const float* __restrict__ W3rel, const float* __restrict__ b3,
             const float* __restrict__ W3root,
             float* __restrict__ z, float* __restrict__ out, int N) {
    __shared__ __align__(16) ushort Xhi[BM2 * XS_LD];
    __shared__ __align__(16) ushort Xlo[BM2 * XS_LD];
    __shared__ __align__(16) ushort Whi[HIDDEN * XS_LD];
    __shared__ __align__(16) ushort Wlo[HIDDEN * XS_LD];
    __shared__ float W3s[HIDDEN * W3_STRIDE];

    const int tid  = threadIdx.x;
    const int lane = tid & 63;
    const int wid  = tid >> 6;
    const int ci   = lane & 15;
    const int kb   = lane >> 4;          // k-block 0..3
    const int nb   = blockIdx.x * BM2;

    if (tid < HIDDEN) {
#pragma unroll
        for (int c = 0; c < 3; ++c) {
            W3s[tid * W3_STRIDE + c]     = W3rel [tid * 3 + c];
            W3s[tid * W3_STRIDE + 3 + c] = W3root[tid * 3 + c];
        }
    }

    f32x4 acc[8];
#pragma unroll
    for (int tile = 0; tile < 8; ++tile) {
        float bb = b[tile * 16 + ci];
        f32x4 v; v[0] = bb; v[1] = bb; v[2] = bb; v[3] = bb;
        acc[tile] = v;
    }

    // staging index precompute
    const int sr  = tid >> 2;            // X row 0..63
    const int skq = (tid & 3) * 8;       // X k offset {0,8,16,24}
    const int wn0 = (tid & 31) * 4;      // W n base (0..124)
    const int wk0 = (tid >> 5) * 4;      // W k base {0,4,...,28}

    // K = 256: 8 phases of 32. t<4: aggr @ Wrel; t>=4: h @ Wroot.
    for (int t = 0; t < 8; ++t) {
        const ushort* Ahi  = (t < 4) ? a_hi : h_hi;
        const ushort* Alo  = (t < 4) ? a_lo : h_lo;
        const float*  Wsrc = (t < 4) ? Wrel : Wroot;
        const int kc = (t & 3) * 32;

        __syncthreads();                 // previous compute done before overwrite
        // stage X tile (pre-split bf16): 1 b128 per array per thread
        {
            int gr = nb + sr; if (gr >= N) gr = N - 1;
            size_t gofs = (size_t)gr * HIDDEN + kc + skq;
            *reinterpret_cast<short8*>(&Xhi[sr * XS_LD + skq]) =
                *reinterpret_cast<const short8*>(Ahi + gofs);
            *reinterpret_cast<short8*>(&Xlo[sr * XS_LD + skq]) =
                *reinterpret_cast<const short8*>(Alo + gofs);
        }
        // stage W tile: read f32 [k][n], split, write transposed [n][k]
        {
            float wv_[4][4];             // [k][j]
#pragma unroll
            for (int i = 0; i < 4; ++i) {
                float4 w4 = *reinterpret_cast<const float4*>(
                    Wsrc + (size_t)(kc + wk0 + i) * HIDDEN + wn0);
                wv_[i][0] = w4.x; wv_[i][1] = w4.y; wv_[i][2] = w4.z; wv_[i][3] = w4.w;
            }
#pragma unroll
            for (int j = 0; j < 4; ++j) {
                ushort4 h4, l4;
                ushort* hp = reinterpret_cast<ushort*>(&h4);
                ushort* lp = reinterpret_cast<ushort*>(&l4);
#pragma unroll
                for (int i = 0; i < 4; ++i) {
                    ushort hb = f2bf(wv_[i][j]);
                    hp[i] = hb;
                    lp[i] = f2bf(wv_[i][j] - bf2f(hb));
                }
                int n = wn0 + j;
                *reinterpret_cast<ushort4*>(&Whi[n * XS_LD + wk0]) = h4;
                *reinterpret_cast<ushort4*>(&Wlo[n * XS_LD + wk0]) = l4;
            }
        }
        __syncthreads();

        // A frags for this wave's 16-row tile (shared across all col tiles)
        int rl = wid * 16 + ci;
        short8 afh = *reinterpret_cast<const short8*>(&Xhi[rl * XS_LD + kb * 8]);
        short8 afl = *reinterpret_cast<const short8*>(&Xlo[rl * XS_LD + kb * 8]);
#pragma unroll
        for (int tile = 0; tile < 8; ++tile) {
            int nl = tile * 16 + ci;
            short8 bfh = *reinterpret_cast<const short8*>(&Whi[nl * XS_LD + kb * 8]);
            short8 bfl = *reinterpret_cast<const short8*>(&Wlo[nl * XS_LD + kb * 8]);
            acc[tile] = __builtin_amdgcn_mfma_f32_16x16x32_bf16(afh, bfh, acc[tile], 0, 0, 0);
            acc[tile] = __builtin_amdgcn_mfma_f32_16x16x32_bf16(afh, bfl, acc[tile], 0, 0, 0);
            acc[tile] = __builtin_amdgcn_mfma_f32_16x16x32_bf16(afl, bfh, acc[tile], 0, 0, 0);
        }
    }

    // epilogue: relu -> per-thread rank-8 partials vs LDS W3 -> width-16 shfl
    // D layout: value (row = kb*4 + m within wave tile, ch = tile*16 + ci)
    const float b30 = b3[0], b31 = b3[1], b32 = b3[2];
#pragma unroll
    for (int m = 0; m < 4; ++m) {
        int node = nb + wid * 16 + kb * 4 + m;
        float zr0 = 0.f, zr1 = 0.f, zr2 = 0.f;
        float zo0 = 0.f, zo1 = 0.f, zo2 = 0.f;
#pragma unroll
        for (int tile = 0; tile < 8; ++tile) {
            float hv = fmaxf(acc[tile][m], 0.f);
            const float* w3 = &W3s[(tile * 16 + ci) * W3_STRIDE];
            zr0 = fmaf(hv, w3[0], zr0); zr1 = fmaf(hv, w3[1], zr1); zr2 = fmaf(hv, w3[2], zr2);
            zo0 = fmaf(hv, w3[3], zo0); zo1 = fmaf(hv, w3[4], zo1); zo2 = fmaf(hv, w3[5], zo2);
        }
#pragma unroll
        for (int d = 8; d >= 1; d >>= 1) {
            zr0 += __shfl_down(zr0, d, 16);
            zr1 += __shfl_down(zr1, d, 16);
            zr2 += __shfl_down(zr2, d, 16);
            zo0 += __shfl_down(zo0, d, 16);
            zo1 += __shfl_down(zo1, d, 16);
            zo2 += __shfl_down(zo2, d, 16);
        }
        if (ci == 0 && node < N) {
            z[(size_t)node * 3 + 0] = zr0;
            z[(size_t)node * 3 + 1] = zr1;
            z[(size_t)node * 3 + 2] = zr2;
            out[(size_t)node * 3 + 0] = zo0 + b30;
            out[(size_t)node * 3 + 1] = zo1 + b31;
            out[(size_t)node * 3 + 2] = zo2 + b32;
        }
    }
}

// ================= layer 3 gather =====================
__global__ __launch_bounds__(256)
void k_gather3(const int* __restrict__ offs, const int2* __restrict__ cpack,
               const float* __restrict__ z, float* __restrict__ out,
               int N, int E) {
    int i = blockIdx.x * 256 + threadIdx.x;
    if (i >= N) return;
    int start = offs[i], end = end_of(offs, i, N, E);
    float a0 = 0.f, a1 = 0.f, a2 = 0.f;
    for (int j = start; j < end; ++j) {
        int2  p = cpack[j];
        int   s = p.x;
        float w = __int_as_float(p.y);
        const float* zp = z + (size_t)s * 3;
        a0 = fmaf(w, zp[0], a0);
        a1 = fmaf(w, zp[1], a1);
        a2 = fmaf(w, zp[2], a2);
    }
    out[(size_t)i * 3 + 0] += a0;
    out[(size_t)i * 3 + 1] += a1;
    out[(size_t)i * 3 + 2] += a2;
}

extern "C" void kernel_launch(void* const* d_in, const int* in_sizes, int n_in,
                              void* d_out, int out_size, void* d_ws, size_t ws_size,
                              hipStream_t stream) {
    const float* x      = (const float*)d_in[0];
    const int*   ei     = (const int*)  d_in[1];
    const float* ew     = (const float*)d_in[2];
    const float* W1rel  = (const float*)d_in[4];
    const float* b1     = (const float*)d_in[5];
    const float* W1root = (const float*)d_in[6];
    const float* W2rel  = (const float*)d_in[7];
    const float* b2     = (const float*)d_in[8];
    const float* W2root = (const float*)d_in[9];
    const float* W3rel  = (const float*)d_in[10];
    const float* b3     = (const float*)d_in[11];
    const float* W3root = (const float*)d_in[12];
    float* out = (float*)d_out;

    const int N = in_sizes[0] / 2;
    const int E = in_sizes[2];
    const int* src = ei;
    const int* dst = ei + E;

    // -------- workspace layout (same total size as R13) --------
    // h region  : N*128*4B -> h_hi[N*128 bf16] + h_lo[N*128 bf16]
    //             (front E ints alias rank during CSR build)
    // aggr reg. : N*128*4B -> a_hi + a_lo (bf16)
    // offs : N int | bsum : SCAN_B int
    // cpack : E int2 (front N ints alias cnt)
    // yv : N float4 (dead after gatherfused; front N*3 f32 = z)
    ushort* h_hi = (ushort*)d_ws;
    ushort* h_lo = h_hi + (size_t)N * HIDDEN;
    ushort* a_hi = h_lo + (size_t)N * HIDDEN;
    ushort* a_lo = a_hi + (size_t)N * HIDDEN;
    int*   offs = (int*)(a_lo + (size_t)N * HIDDEN);
    int*   bsum = offs + N;
    size_t cpo  = (size_t)(bsum + SCAN_B - (int*)d_ws);
    cpo = (cpo + 1) & ~(size_t)1;          // 8B alignment
    int2*   cpack = (int2*)((int*)d_ws + cpo);
    size_t yvo  = (size_t)((char*)(cpack + E) - (char*)d_ws);
    yvo = (yvo + 15) & ~(size_t)15;        // 16B alignment
    float4* yv  = (float4*)((char*)d_ws + yvo);
    int* cnt  = (int*)cpack;               // alias: dead before k_fill writes cpack
    int* rank = (int*)d_ws;                // alias: dead before gatherfused writes h_hi
    float* z  = (float*)yv;                // alias: yv dead after gatherfused

    const int nbScan = (N + SCAN_B - 1) / SCAN_B;

    // -------- CSR build --------
    hipMemsetAsync(cnt, 0, (size_t)N * sizeof(int), stream);
    k_hist <<<(E + 255) / 256, 256, 0, stream>>>(dst, cnt, rank, E);
    k_scan1<<<nbScan, SCAN_B, 0, stream>>>(cnt, offs, bsum, N);
    k_scan2<<<1, SCAN_B, 0, stream>>>(bsum, nbScan);
    k_scan3<<<nbScan, SCAN_B, 0, stream>>>(offs, bsum, N);
    k_fill <<<(E + 255) / 256, 256, 0, stream>>>(src, dst, ew, offs, rank, cpack, E);

    // -------- layer 1 aggregation (2ch) + y pack --------
    k_gather2<<<(N + 255) / 256, 256, 0, stream>>>(offs, cpack, x, yv, N, E);

    // -------- fused layer-2 aggregation + layer-1 node update (bf16 out) ----
    {
        long long threads = (long long)N * 64;
        k_gatherfused<<<(int)((threads + 255) / 256), 256, 0, stream>>>(
            offs, cpack, yv, W1rel, b1, W1root, h_hi, h_lo, a_hi, a_lo, N, E);
    }

    // -------- MFMA layer-2 node update + layer-3 projection --------
    k_node2<<<(N + BM2 - 1) / BM2, 256, 0, stream>>>(
        a_hi, a_lo, h_hi, h_lo, W2rel, b2, W2root, W3rel, b3, W3root, z, out, N);

    // -------- layer 3 gather --------
    k_gather3<<<(N + 255) / 256, 256, 0, stream>>>(offs, cpack, z, out, N, E);
}

// Round 15
// 265.545 us; speedup vs baseline: 1.4171x; 1.0562x over previous
//
#include <hip/hip_runtime.h>

#define HIDDEN 128
#define SCAN_B 1024

typedef float v2f __attribute__((ext_vector_type(2)));
typedef short short8 __attribute__((ext_vector_type(8)));
typedef float f32x4 __attribute__((ext_vector_type(4)));
__device__ __forceinline__ v2f v2s(float a) { v2f r; r.x = a; r.y = a; return r; }

// bf16 split helpers (RNE)
__device__ __forceinline__ ushort f2bf(float f) {
    uint u = __float_as_uint(f);
    u += 0x7FFFu + ((u >> 16) & 1u);
    return (ushort)(u >> 16);
}
__device__ __forceinline__ float bf2f(ushort h) {
    return __uint_as_float(((uint)h) << 16);
}

// ================= CSR build (per call; no fp atomics anywhere) =============
__global__ __launch_bounds__(256)
void k_hist(const int* __restrict__ dst, int* __restrict__ cnt,
            int* __restrict__ rank, int E) {
    int e = blockIdx.x * 256 + threadIdx.x;
    if (e < E) rank[e] = atomicAdd(&cnt[dst[e]], 1);
}

__global__ __launch_bounds__(SCAN_B)
void k_scan1(const int* __restrict__ cnt, int* __restrict__ offs,
             int* __restrict__ bsum, int N) {
    __shared__ int sm[SCAN_B];
    int g = blockIdx.x * SCAN_B + threadIdx.x;
    int v = (g < N) ? cnt[g] : 0;
    int acc = v;
    sm[threadIdx.x] = v;
    __syncthreads();
    for (int d = 1; d < SCAN_B; d <<= 1) {
        int t = (threadIdx.x >= d) ? sm[threadIdx.x - d] : 0;
        __syncthreads();
        acc += t;
        sm[threadIdx.x] = acc;
        __syncthreads();
    }
    if (g < N) offs[g] = acc - v;                 // exclusive
    if (threadIdx.x == SCAN_B - 1) bsum[blockIdx.x] = acc;
}

__global__ __launch_bounds__(SCAN_B)
void k_scan2(int* __restrict__ bsum, int nb) {
    __shared__ int sm[SCAN_B];
    int v = (threadIdx.x < nb) ? bsum[threadIdx.x] : 0;
    int acc = v;
    sm[threadIdx.x] = v;
    __syncthreads();
    for (int d = 1; d < SCAN_B; d <<= 1) {
        int t = (threadIdx.x >= d) ? sm[threadIdx.x - d] : 0;
        __syncthreads();
        acc += t;
        sm[threadIdx.x] = acc;
        __syncthreads();
    }
    if (threadIdx.x < nb) bsum[threadIdx.x] = acc - v;   // exclusive
}

__global__ __launch_bounds__(SCAN_B)
void k_scan3(int* __restrict__ offs, const int* __restrict__ bsum, int N) {
    int g = blockIdx.x * SCAN_B + threadIdx.x;
    if (g < N) offs[g] += bsum[blockIdx.x];
}

// Scatter edges into CSR order. One 8B packed store per edge (src, w).
__global__ __launch_bounds__(256)
void k_fill(const int* __restrict__ src, const int* __restrict__ dst,
            const float* __restrict__ ew, const int* __restrict__ offs,
            const int* __restrict__ rank, int2* __restrict__ cpack, int E) {
    int e = blockIdx.x * 256 + threadIdx.x;
    if (e >= E) return;
    int d = dst[e];
    int slot = offs[d] + rank[e];
    int2 p;
    p.x = src[e];
    p.y = __float_as_int(ew[e]);
    cpack[slot] = p;
}

__device__ __forceinline__ int end_of(const int* offs, int i, int N, int E) {
    return (i + 1 < N) ? offs[i + 1] : E;
}

// ================= layer 1: gather 2ch, emit combined y = (a0,a1,x0,x1) ====
__global__ __launch_bounds__(256)
void k_gather2(const int* __restrict__ offs, const int2* __restrict__ cpack,
               const float* __restrict__ x, float4* __restrict__ yv,
               int N, int E) {
    int i = blockIdx.x * 256 + threadIdx.x;
    if (i >= N) return;
    int start = offs[i], end = end_of(offs, i, N, E);
    float a0 = 0.f, a1 = 0.f;
    for (int j = start; j < end; ++j) {
        int2  p = cpack[j];
        int   s = p.x;
        float w = __int_as_float(p.y);
        float2 xv = *reinterpret_cast<const float2*>(x + (size_t)s * 2);
        a0 = fmaf(w, xv.x, a0);
        a1 = fmaf(w, xv.y, a1);
    }
    float2 xi = *reinterpret_cast<const float2*>(x + (size_t)i * 2);
    yv[i] = make_float4(a0, a1, xi.x, xi.y);
}

// ================= fused layer-2 aggregation + layer-1 node update ==========
// (R8 structure) — epilogue emits bf16 hi/lo splits of aggr and h1.
#define EDGE4(sK, wK)                                              \
    {                                                              \
        v2f t = B + v2s((sK).x) * WR0 + v2s((sK).y) * WR1          \
                  + v2s((sK).z) * WO0 + v2s((sK).w) * WO1;         \
        t = __builtin_elementwise_max(t, Z);                       \
        acc = acc + v2s(wK) * t;                                   \
    }

__global__ __launch_bounds__(256)
void k_gatherfused(const int* __restrict__ offs, const int2* __restrict__ cpack,
                   const float4* __restrict__ yv,
                   const float* __restrict__ W1rel, const float* __restrict__ b1,
                   const float* __restrict__ W1root,
                   ushort* __restrict__ h_hi, ushort* __restrict__ h_lo,
                   ushort* __restrict__ a_hi, ushort* __restrict__ a_lo,
                   int N, int E) {
    int wv   = (blockIdx.x * 256 + threadIdx.x) >> 6;
    int lane = threadIdx.x & 63;
    if (wv >= N) return;

    const int c0 = lane * 2;
    const v2f WR0 = *reinterpret_cast<const v2f*>(W1rel  + c0);
    const v2f WR1 = *reinterpret_cast<const v2f*>(W1rel  + HIDDEN + c0);
    const v2f WO0 = *reinterpret_cast<const v2f*>(W1root + c0);
    const v2f WO1 = *reinterpret_cast<const v2f*>(W1root + HIDDEN + c0);
    const v2f B   = *reinterpret_cast<const v2f*>(b1 + c0);
    const v2f Z   = {0.f, 0.f};

    int start = offs[wv], end = end_of(offs, wv, N, E);
    v2f acc = {0.f, 0.f};

    for (int base = start; base < end; base += 64) {
        int nb = min(64, end - base);
        int sx = 0, wb = 0;
        if (lane < nb) {                       // one coalesced 8B/lane load
            int2 p = cpack[base + lane];
            sx = p.x; wb = p.y;
        }
        int k = 0;
        for (; k + 8 <= nb; k += 8) {          // 8 loads in flight
            int s0 = __shfl(sx, k),     s1 = __shfl(sx, k + 1);
            int s2 = __shfl(sx, k + 2), s3 = __shfl(sx, k + 3);
            int s4 = __shfl(sx, k + 4), s5 = __shfl(sx, k + 5);
            int s6 = __shfl(sx, k + 6), s7 = __shfl(sx, k + 7);
            float w0 = __int_as_float(__shfl(wb, k));
            float w1 = __int_as_float(__shfl(wb, k + 1));
            float w2 = __int_as_float(__shfl(wb, k + 2));
            float w3 = __int_as_float(__shfl(wb, k + 3));
            float w4 = __int_as_float(__shfl(wb, k + 4));
            float w5 = __int_as_float(__shfl(wb, k + 5));
            float w6 = __int_as_float(__shfl(wb, k + 6));
            float w7 = __int_as_float(__shfl(wb, k + 7));
            float4 y0 = yv[s0]; float4 y1 = yv[s1];
            float4 y2 = yv[s2]; float4 y3 = yv[s3];
            float4 y4 = yv[s4]; float4 y5 = yv[s5];
            float4 y6 = yv[s6]; float4 y7 = yv[s7];
            EDGE4(y0, w0) EDGE4(y1, w1) EDGE4(y2, w2) EDGE4(y3, w3)
            EDGE4(y4, w4) EDGE4(y5, w5) EDGE4(y6, w6) EDGE4(y7, w7)
        }
        for (; k + 4 <= nb; k += 4) {          // 4-deep middle tier
            int s0 = __shfl(sx, k),     s1 = __shfl(sx, k + 1);
            int s2 = __shfl(sx, k + 2), s3 = __shfl(sx, k + 3);
            float w0 = __int_as_float(__shfl(wb, k));
            float w1 = __int_as_float(__shfl(wb, k + 1));
            float w2 = __int_as_float(__shfl(wb, k + 2));
            float w3 = __int_as_float(__shfl(wb, k + 3));
            float4 y0 = yv[s0]; float4 y1 = yv[s1];
            float4 y2 = yv[s2]; float4 y3 = yv[s3];
            EDGE4(y0, w0) EDGE4(y1, w1) EDGE4(y2, w2) EDGE4(y3, w3)
        }
        for (; k < nb; ++k) {                  // scalar tail (<=3)
            int   s0 = __shfl(sx, k);
            float w0 = __int_as_float(__shfl(wb, k));
            float4 y0 = yv[s0];
            EDGE4(y0, w0)
        }
    }

    // aggr -> bf16 hi/lo
    {
        ushort hx = f2bf(acc.x);
        ushort lx = f2bf(acc.x - bf2f(hx));
        ushort hy = f2bf(acc.y);
        ushort ly = f2bf(acc.y - bf2f(hy));
        ushort2 hv2; hv2.x = hx; hv2.y = hy;
        ushort2 lv2; lv2.x = lx; lv2.y = ly;
        *reinterpret_cast<ushort2*>(a_hi + (size_t)wv * HIDDEN + c0) = hv2;
        *reinterpret_cast<ushort2*>(a_lo + (size_t)wv * HIDDEN + c0) = lv2;
    }

    // fused k_node1: this wave's own h1 row -> bf16 hi/lo
    {
        float4 y = yv[wv];
        v2f t = B + v2s(y.x) * WR0 + v2s(y.y) * WR1
                  + v2s(y.z) * WO0 + v2s(y.w) * WO1;
        t = __builtin_elementwise_max(t, Z);
        ushort hx = f2bf(t.x);
        ushort lx = f2bf(t.x - bf2f(hx));
        ushort hy = f2bf(t.y);
        ushort ly = f2bf(t.y - bf2f(hy));
        ushort2 hv2; hv2.x = hx; hv2.y = hy;
        ushort2 lv2; lv2.x = lx; lv2.y = ly;
        *reinterpret_cast<ushort2*>(h_hi + (size_t)wv * HIDDEN + c0) = hv2;
        *reinterpret_cast<ushort2*>(h_lo + (size_t)wv * HIDDEN + c0) = lv2;
    }
}

// ================= one-shot W2 split + transpose ============================
// wT[hi/lo][n=128][K=256] bf16: K 0..127 = W2rel rows, 128..255 = W2root rows.
// Removes the per-phase per-block W split (was ~110 VALU/thread/phase in
// node2, re-splitting the same 32K values ~12K times) and halves W staging
// bytes. Runs once (~3us); result is L2-hot for all node2 blocks.
__global__ __launch_bounds__(256)
void k_splitw(const float* __restrict__ Wrel, const float* __restrict__ Wroot,
              ushort* __restrict__ wThi, ushort* __restrict__ wTlo) {
    int idx = blockIdx.x * 256 + threadIdx.x;   // 0..32767
    int k = idx >> 7;          // 0..255
    int n = idx & 127;
    float v = (k < 128) ? Wrel[(size_t)k * HIDDEN + n]
                        : Wroot[(size_t)(k - 128) * HIDDEN + n];
    ushort hb = f2bf(v);
    ushort lb = f2bf(v - bf2f(hb));
    wThi[(size_t)n * 256 + k] = hb;
    wTlo[(size_t)n * 256 + k] = lb;
}

// ============ layer-2 node update on the MATRIX pipe + layer-3 fusion =======
// R15: R14's MFMA kernel with W staging as a pure b128 copy from the
// pre-split pre-transposed wT arrays (zero staging VALU, no t<4/>=4 W branch).
#define BM2 64
#define W3_STRIDE 7
#define XS_LD 40   // ushorts per LDS row: 32 k + 8 pad (80B, 16B-aligned)

__global__ __launch_bounds__(256)
void k_node2(const ushort* __restrict__ a_hi, const ushort* __restrict__ a_lo,
             const ushort* __restrict__ h_hi, const ushort* __restrict__ h_lo,
             const ushort* __restrict__ wThi, const ushort* __restrict__ wTlo,
             const float* __restrict__ b,
             const float* __restrict__ W3rel, const float* __restrict__ b3,
             const float* __restrict__ W3root,
             float* __restrict__ z, float* __restrict__ out, int N) {
    __shared__ __align__(16) ushort Xhi[BM2 * XS_LD];
    __shared__ __align__(16) ushort Xlo[BM2 * XS_LD];
    __shared__ __align__(16) ushort Whi[HIDDEN * XS_LD];
    __shared__ __align__(16) ushort Wlo[HIDDEN * XS_LD];
    __shared__ float W3s[HIDDEN * W3_STRIDE];

    const int tid  = threadIdx.x;
    const int lane = tid & 63;
    const int wid  = tid >> 6;
    const int ci   = lane & 15;
    const int kb   = lane >> 4;          // k-block 0..3
    const int nb   = blockIdx.x * BM2;

    if (tid < HIDDEN) {
#pragma unroll
        for (int c = 0; c < 3; ++c) {
            W3s[tid * W3_STRIDE + c]     = W3rel [tid * 3 + c];
            W3s[tid * W3_STRIDE + 3 + c] = W3root[tid * 3 + c];
        }
    }

    f32x4 acc[8];
#pragma unroll
    for (int tile = 0; tile < 8; ++tile) {
        float bb = b[tile * 16 + ci];
        f32x4 v; v[0] = bb; v[1] = bb; v[2] = bb; v[3] = bb;
        acc[tile] = v;
    }

    // staging index precompute
    const int sr  = tid >> 2;            // X row 0..63
    const int skq = (tid & 3) * 8;       // X k offset {0,8,16,24}
    const int wn  = tid >> 1;            // W n rows: idx scheme below
    // K = 256: 8 phases of 32. t<4: aggr; t>=4: h. W index is linear in t.
    for (int t = 0; t < 8; ++t) {
        const ushort* Ahi = (t < 4) ? a_hi : h_hi;
        const ushort* Alo = (t < 4) ? a_lo : h_lo;
        const int kc = (t & 3) * 32;

        __syncthreads();                 // previous compute done before overwrite
        // stage X tile (pre-split bf16): 1 b128 per array per thread
        {
            int gr = nb + sr; if (gr >= N) gr = N - 1;
            size_t gofs = (size_t)gr * HIDDEN + kc + skq;
            *reinterpret_cast<short8*>(&Xhi[sr * XS_LD + skq]) =
                *reinterpret_cast<const short8*>(Ahi + gofs);
            *reinterpret_cast<short8*>(&Xlo[sr * XS_LD + skq]) =
                *reinterpret_cast<const short8*>(Alo + gofs);
        }
        // stage W tile: pure b128 copy from pre-split pre-transposed wT
#pragma unroll
        for (int q = 0; q < 2; ++q) {
            int idx = q * 256 + tid;     // 0..511
            int n  = idx >> 2;           // 0..127
            int kq = (idx & 3) * 8;      // 0,8,16,24
            size_t g = (size_t)n * 256 + t * 32 + kq;
            *reinterpret_cast<short8*>(&Whi[n * XS_LD + kq]) =
                *reinterpret_cast<const short8*>(wThi + g);
            *reinterpret_cast<short8*>(&Wlo[n * XS_LD + kq]) =
                *reinterpret_cast<const short8*>(wTlo + g);
        }
        __syncthreads();

        // A frags for this wave's 16-row tile (shared across all col tiles)
        int rl = wid * 16 + ci;
        short8 afh = *reinterpret_cast<const short8*>(&Xhi[rl * XS_LD + kb * 8]);
        short8 afl = *reinterpret_cast<const short8*>(&Xlo[rl * XS_LD + kb * 8]);
#pragma unroll
        for (int tile = 0; tile < 8; ++tile) {
            int nl = tile * 16 + ci;
            short8 bfh = *reinterpret_cast<const short8*>(&Whi[nl * XS_LD + kb * 8]);
            short8 bfl = *reinterpret_cast<const short8*>(&Wlo[nl * XS_LD + kb * 8]);
            acc[tile] = __builtin_amdgcn_mfma_f32_16x16x32_bf16(afh, bfh, acc[tile], 0, 0, 0);
            acc[tile] = __builtin_amdgcn_mfma_f32_16x16x32_bf16(afh, bfl, acc[tile], 0, 0, 0);
            acc[tile] = __builtin_amdgcn_mfma_f32_16x16x32_bf16(afl, bfh, acc[tile], 0, 0, 0);
        }
    }

    // epilogue: relu -> per-thread rank-8 partials vs LDS W3 -> width-16 shfl
    // D layout: row = kb*4 + m within wave tile, ch = tile*16 + ci
    const float b30 = b3[0], b31 = b3[1], b32 = b3[2];
#pragma unroll
    for (int m = 0; m < 4; ++m) {
        int node = nb + wid * 16 + kb * 4 + m;
        float zr0 = 0.f, zr1 = 0.f, zr2 = 0.f;
        float zo0 = 0.f, zo1 = 0.f, zo2 = 0.f;
#pragma unroll
        for (int tile = 0; tile < 8; ++tile) {
            float hv = fmaxf(acc[tile][m], 0.f);
            const float* w3 = &W3s[(tile * 16 + ci) * W3_STRIDE];
            zr0 = fmaf(hv, w3[0], zr0); zr1 = fmaf(hv, w3[1], zr1); zr2 = fmaf(hv, w3[2], zr2);
            zo0 = fmaf(hv, w3[3], zo0); zo1 = fmaf(hv, w3[4], zo1); zo2 = fmaf(hv, w3[5], zo2);
        }
#pragma unroll
        for (int d = 8; d >= 1; d >>= 1) {
            zr0 += __shfl_down(zr0, d, 16);
            zr1 += __shfl_down(zr1, d, 16);
            zr2 += __shfl_down(zr2, d, 16);
            zo0 += __shfl_down(zo0, d, 16);
            zo1 += __shfl_down(zo1, d, 16);
            zo2 += __shfl_down(zo2, d, 16);
        }
        if (ci == 0 && node < N) {
            z[(size_t)node * 3 + 0] = zr0;
            z[(size_t)node * 3 + 1] = zr1;
            z[(size_t)node * 3 + 2] = zr2;
            out[(size_t)node * 3 + 0] = zo0 + b30;
            out[(size_t)node * 3 + 1] = zo1 + b31;
            out[(size_t)node * 3 + 2] = zo2 + b32;
        }
    }
}

// ================= layer 3 gather =====================
__global__ __launch_bounds__(256)
void k_gather3(const int* __restrict__ offs, const int2* __restrict__ cpack,
               const float* __restrict__ z, float* __restrict__ out,
               int N, int E) {
    int i = blockIdx.x * 256 + threadIdx.x;
    if (i >= N) return;
    int start = offs[i], end = end_of(offs, i, N, E);
    float a0 = 0.f, a1 = 0.f, a2 = 0.f;
    for (int j = start; j < end; ++j) {
        int2  p = cpack[j];
        int   s = p.x;
        float w = __int_as_float(p.y);
        const float* zp = z + (size_t)s * 3;
        a0 = fmaf(w, zp[0], a0);
        a1 = fmaf(w, zp[1], a1);
        a2 = fmaf(w, zp[2], a2);
    }
    out[(size_t)i * 3 + 0] += a0;
    out[(size_t)i * 3 + 1] += a1;
    out[(size_t)i * 3 + 2] += a2;
}

extern "C" void kernel_launch(void* const* d_in, const int* in_sizes, int n_in,
                              void* d_out, int out_size, void* d_ws, size_t ws_size,
                              hipStream_t stream) {
    const float* x      = (const float*)d_in[0];
    const int*   ei     = (const int*)  d_in[1];
    const float* ew     = (const float*)d_in[2];
    const float* W1rel  = (const float*)d_in[4];
    const float* b1     = (const float*)d_in[5];
    const float* W1root = (const float*)d_in[6];
    const float* W2rel  = (const float*)d_in[7];
    const float* b2     = (const float*)d_in[8];
    const float* W2root = (const float*)d_in[9];
    const float* W3rel  = (const float*)d_in[10];
    const float* b3     = (const float*)d_in[11];
    const float* W3root = (const float*)d_in[12];
    float* out = (float*)d_out;

    const int N = in_sizes[0] / 2;
    const int E = in_sizes[2];
    const int* src = ei;
    const int* dst = ei + E;

    // -------- workspace layout (same total size as R14) --------
    // h region  : h_hi[N*128 bf16] + h_lo  (front E ints alias rank in CSR build)
    // aggr reg. : a_hi + a_lo (bf16)
    // offs : N int | bsum : SCAN_B int
    // cpack : E int2 (front N ints alias cnt)
    // yv : N float4 (dead after gatherfused):
    //      front N*3 f32 = z; tail (>=400KB free) holds wThi/wTlo (128KB)
    ushort* h_hi = (ushort*)d_ws;
    ushort* h_lo = h_hi + (size_t)N * HIDDEN;
    ushort* a_hi = h_lo + (size_t)N * HIDDEN;
    ushort* a_lo = a_hi + (size_t)N * HIDDEN;
    int*   offs = (int*)(a_lo + (size_t)N * HIDDEN);
    int*   bsum = offs + N;
    size_t cpo  = (size_t)(bsum + SCAN_B - (int*)d_ws);
    cpo = (cpo + 1) & ~(size_t)1;          // 8B alignment
    int2*   cpack = (int2*)((int*)d_ws + cpo);
    size_t yvo  = (size_t)((char*)(cpack + E) - (char*)d_ws);
    yvo = (yvo + 15) & ~(size_t)15;        // 16B alignment
    float4* yv  = (float4*)((char*)d_ws + yvo);
    int* cnt  = (int*)cpack;               // alias: dead before k_fill writes cpack
    int* rank = (int*)d_ws;                // alias: dead before gatherfused writes h_hi
    float* z  = (float*)yv;                // alias: yv dead after gatherfused
    size_t wto = yvo + ((size_t)N * 3 * sizeof(float) + 15 & ~(size_t)15);
    wto = (wto + 15) & ~(size_t)15;
    ushort* wThi = (ushort*)((char*)d_ws + wto);          // 64KB
    ushort* wTlo = wThi + 128 * 256;                       // 64KB (within yv tail)

    const int nbScan = (N + SCAN_B - 1) / SCAN_B;

    // -------- CSR build --------
    hipMemsetAsync(cnt, 0, (size_t)N * sizeof(int), stream);
    k_hist <<<(E + 255) / 256, 256, 0, stream>>>(dst, cnt, rank, E);
    k_scan1<<<nbScan, SCAN_B, 0, stream>>>(cnt, offs, bsum, N);
    k_scan2<<<1, SCAN_B, 0, stream>>>(bsum, nbScan);
    k_scan3<<<nbScan, SCAN_B, 0, stream>>>(offs, bsum, N);
    k_fill <<<(E + 255) / 256, 256, 0, stream>>>(src, dst, ew, offs, rank, cpack, E);

    // -------- layer 1 aggregation (2ch) + y pack --------
    k_gather2<<<(N + 255) / 256, 256, 0, stream>>>(offs, cpack, x, yv, N, E);

    // -------- fused layer-2 aggregation + layer-1 node update (bf16 out) ----
    {
        long long threads = (long long)N * 64;
        k_gatherfused<<<(int)((threads + 255) / 256), 256, 0, stream>>>(
            offs, cpack, yv, W1rel, b1, W1root, h_hi, h_lo, a_hi, a_lo, N, E);
    }

    // -------- one-shot W2 split+transpose (yv dead now; writes its tail) ----
    k_splitw<<<128, 256, 0, stream>>>(W2rel, W2root, wThi, wTlo);

    // -------- MFMA layer-2 node update + layer-3 projection --------
    k_node2<<<(N + BM2 - 1) / BM2, 256, 0, stream>>>(
        a_hi, a_lo, h_hi, h_lo, wThi, wTlo, b2, W3rel, b3, W3root, z, out, N);

    // -------- layer 3 gather --------
    k_gather3<<<(N + 255) / 256, 256, 0, stream>>>(offs, cpack, z, out, N, E);
}

// Round 16
// 255.860 us; speedup vs baseline: 1.4708x; 1.0379x over previous
//
#include <hip/hip_runtime.h>

#define HIDDEN 128
#define SCAN_B 1024

typedef float v2f __attribute__((ext_vector_type(2)));
typedef short short8 __attribute__((ext_vector_type(8)));
typedef float f32x4 __attribute__((ext_vector_type(4)));
__device__ __forceinline__ v2f v2s(float a) { v2f r; r.x = a; r.y = a; return r; }

// bf16 split helpers (RNE)
__device__ __forceinline__ ushort f2bf(float f) {
    uint u = __float_as_uint(f);
    u += 0x7FFFu + ((u >> 16) & 1u);
    return (ushort)(u >> 16);
}
__device__ __forceinline__ float bf2f(ushort h) {
    return __uint_as_float(((uint)h) << 16);
}

// ================= CSR build (per call; no fp atomics anywhere) =============
__global__ __launch_bounds__(256)
void k_hist(const int* __restrict__ dst, int* __restrict__ cnt,
            int* __restrict__ rank, int E) {
    int e = blockIdx.x * 256 + threadIdx.x;
    if (e < E) rank[e] = atomicAdd(&cnt[dst[e]], 1);
}

__global__ __launch_bounds__(SCAN_B)
void k_scan1(const int* __restrict__ cnt, int* __restrict__ offs,
             int* __restrict__ bsum, int N) {
    __shared__ int sm[SCAN_B];
    int g = blockIdx.x * SCAN_B + threadIdx.x;
    int v = (g < N) ? cnt[g] : 0;
    int acc = v;
    sm[threadIdx.x] = v;
    __syncthreads();
    for (int d = 1; d < SCAN_B; d <<= 1) {
        int t = (threadIdx.x >= d) ? sm[threadIdx.x - d] : 0;
        __syncthreads();
        acc += t;
        sm[threadIdx.x] = acc;
        __syncthreads();
    }
    if (g < N) offs[g] = acc - v;                 // exclusive
    if (threadIdx.x == SCAN_B - 1) bsum[blockIdx.x] = acc;
}

__global__ __launch_bounds__(SCAN_B)
void k_scan2(int* __restrict__ bsum, int nb) {
    __shared__ int sm[SCAN_B];
    int v = (threadIdx.x < nb) ? bsum[threadIdx.x] : 0;
    int acc = v;
    sm[threadIdx.x] = v;
    __syncthreads();
    for (int d = 1; d < SCAN_B; d <<= 1) {
        int t = (threadIdx.x >= d) ? sm[threadIdx.x - d] : 0;
        __syncthreads();
        acc += t;
        sm[threadIdx.x] = acc;
        __syncthreads();
    }
    if (threadIdx.x < nb) bsum[threadIdx.x] = acc - v;   // exclusive
}

__global__ __launch_bounds__(SCAN_B)
void k_scan3(int* __restrict__ offs, const int* __restrict__ bsum, int N) {
    int g = blockIdx.x * SCAN_B + threadIdx.x;
    if (g < N) offs[g] += bsum[blockIdx.x];
}

// Scatter edges into CSR order. One 8B packed store per edge (src, w).
__global__ __launch_bounds__(256)
void k_fill(const int* __restrict__ src, const int* __restrict__ dst,
            const float* __restrict__ ew, const int* __restrict__ offs,
            const int* __restrict__ rank, int2* __restrict__ cpack, int E) {
    int e = blockIdx.x * 256 + threadIdx.x;
    if (e >= E) return;
    int d = dst[e];
    int slot = offs[d] + rank[e];
    int2 p;
    p.x = src[e];
    p.y = __float_as_int(ew[e]);
    cpack[slot] = p;
}

__device__ __forceinline__ int end_of(const int* offs, int i, int N, int E) {
    return (i + 1 < N) ? offs[i + 1] : E;
}

// ================= layer 1: gather 2ch, emit combined y = (a0,a1,x0,x1) ====
__global__ __launch_bounds__(256)
void k_gather2(const int* __restrict__ offs, const int2* __restrict__ cpack,
               const float* __restrict__ x, float4* __restrict__ yv,
               int N, int E) {
    int i = blockIdx.x * 256 + threadIdx.x;
    if (i >= N) return;
    int start = offs[i], end = end_of(offs, i, N, E);
    float a0 = 0.f, a1 = 0.f;
    for (int j = start; j < end; ++j) {
        int2  p = cpack[j];
        int   s = p.x;
        float w = __int_as_float(p.y);
        float2 xv = *reinterpret_cast<const float2*>(x + (size_t)s * 2);
        a0 = fmaf(w, xv.x, a0);
        a1 = fmaf(w, xv.y, a1);
    }
    float2 xi = *reinterpret_cast<const float2*>(x + (size_t)i * 2);
    yv[i] = make_float4(a0, a1, xi.x, xi.y);
}

// ================= fused layer-2 aggregation + layer-1 node update ==========
// R16: SCALARIZED edge loop. Every edge-loop value (wv, offs, j, cpack[j],
// s, yv[s], w) is wave-uniform — only the channel math is per-lane. Forcing
// uniformity via readfirstlane turns cpack[j] into s_load_dwordx2 and yv[s]
// into s_load_dwordx4 on the SCALAR pipe: removes 2 ds_bpermute (shfl) +
// 1 VMEM broadcast per edge (R4's attempt failed because tid-derived wv
// defeated divergence analysis — no readfirstlane). 8/4/1 unroll keeps 8
// scalar loads in flight. Epilogue emits bf16 hi/lo splits (R14 structure).
#define EDGE4(sK, wK)                                              \
    {                                                              \
        v2f t = B + v2s((sK).x) * WR0 + v2s((sK).y) * WR1          \
                  + v2s((sK).z) * WO0 + v2s((sK).w) * WO1;         \
        t = __builtin_elementwise_max(t, Z);                       \
        acc = acc + v2s(wK) * t;                                   \
    }

__global__ __launch_bounds__(256)
void k_gatherfused(const int* __restrict__ offs, const int2* __restrict__ cpack,
                   const float4* __restrict__ yv,
                   const float* __restrict__ W1rel, const float* __restrict__ b1,
                   const float* __restrict__ W1root,
                   ushort* __restrict__ h_hi, ushort* __restrict__ h_lo,
                   ushort* __restrict__ a_hi, ushort* __restrict__ a_lo,
                   int N, int E) {
    int wv   = (blockIdx.x * 256 + threadIdx.x) >> 6;
    int lane = threadIdx.x & 63;
    if (wv >= N) return;
    wv = __builtin_amdgcn_readfirstlane(wv);   // force scalar: whole loop uniform

    const int c0 = lane * 2;
    const v2f WR0 = *reinterpret_cast<const v2f*>(W1rel  + c0);
    const v2f WR1 = *reinterpret_cast<const v2f*>(W1rel  + HIDDEN + c0);
    const v2f WO0 = *reinterpret_cast<const v2f*>(W1root + c0);
    const v2f WO1 = *reinterpret_cast<const v2f*>(W1root + HIDDEN + c0);
    const v2f B   = *reinterpret_cast<const v2f*>(b1 + c0);
    const v2f Z   = {0.f, 0.f};

    int start = offs[wv];
    int end   = (wv + 1 < N) ? offs[wv + 1] : E;
    v2f acc = {0.f, 0.f};

    int j = start;
    for (; j + 8 <= end; j += 8) {             // 8 scalar loads in flight
        int2 p0 = cpack[j + 0]; int2 p1 = cpack[j + 1];
        int2 p2 = cpack[j + 2]; int2 p3 = cpack[j + 3];
        int2 p4 = cpack[j + 4]; int2 p5 = cpack[j + 5];
        int2 p6 = cpack[j + 6]; int2 p7 = cpack[j + 7];
        int s0 = __builtin_amdgcn_readfirstlane(p0.x);
        int s1 = __builtin_amdgcn_readfirstlane(p1.x);
        int s2 = __builtin_amdgcn_readfirstlane(p2.x);
        int s3 = __builtin_amdgcn_readfirstlane(p3.x);
        int s4 = __builtin_amdgcn_readfirstlane(p4.x);
        int s5 = __builtin_amdgcn_readfirstlane(p5.x);
        int s6 = __builtin_amdgcn_readfirstlane(p6.x);
        int s7 = __builtin_amdgcn_readfirstlane(p7.x);
        float4 y0 = yv[s0]; float4 y1 = yv[s1];
        float4 y2 = yv[s2]; float4 y3 = yv[s3];
        float4 y4 = yv[s4]; float4 y5 = yv[s5];
        float4 y6 = yv[s6]; float4 y7 = yv[s7];
        float w0 = __int_as_float(p0.y); float w1 = __int_as_float(p1.y);
        float w2 = __int_as_float(p2.y); float w3 = __int_as_float(p3.y);
        float w4 = __int_as_float(p4.y); float w5 = __int_as_float(p5.y);
        float w6 = __int_as_float(p6.y); float w7 = __int_as_float(p7.y);
        EDGE4(y0, w0) EDGE4(y1, w1) EDGE4(y2, w2) EDGE4(y3, w3)
        EDGE4(y4, w4) EDGE4(y5, w5) EDGE4(y6, w6) EDGE4(y7, w7)
    }
    for (; j + 4 <= end; j += 4) {
        int2 p0 = cpack[j + 0]; int2 p1 = cpack[j + 1];
        int2 p2 = cpack[j + 2]; int2 p3 = cpack[j + 3];
        int s0 = __builtin_amdgcn_readfirstlane(p0.x);
        int s1 = __builtin_amdgcn_readfirstlane(p1.x);
        int s2 = __builtin_amdgcn_readfirstlane(p2.x);
        int s3 = __builtin_amdgcn_readfirstlane(p3.x);
        float4 y0 = yv[s0]; float4 y1 = yv[s1];
        float4 y2 = yv[s2]; float4 y3 = yv[s3];
        float w0 = __int_as_float(p0.y); float w1 = __int_as_float(p1.y);
        float w2 = __int_as_float(p2.y); float w3 = __int_as_float(p3.y);
        EDGE4(y0, w0) EDGE4(y1, w1) EDGE4(y2, w2) EDGE4(y3, w3)
    }
    for (; j < end; ++j) {                     // scalar tail (<=3)
        int2 p0 = cpack[j];
        int s0 = __builtin_amdgcn_readfirstlane(p0.x);
        float4 y0 = yv[s0];
        float w0 = __int_as_float(p0.y);
        EDGE4(y0, w0)
    }

    // aggr -> bf16 hi/lo
    {
        ushort hx = f2bf(acc.x);
        ushort lx = f2bf(acc.x - bf2f(hx));
        ushort hy = f2bf(acc.y);
        ushort ly = f2bf(acc.y - bf2f(hy));
        ushort2 hv2; hv2.x = hx; hv2.y = hy;
        ushort2 lv2; lv2.x = lx; lv2.y = ly;
        *reinterpret_cast<ushort2*>(a_hi + (size_t)wv * HIDDEN + c0) = hv2;
        *reinterpret_cast<ushort2*>(a_lo + (size_t)wv * HIDDEN + c0) = lv2;
    }

    // fused k_node1: this wave's own h1 row -> bf16 hi/lo
    {
        float4 y = yv[wv];
        v2f t = B + v2s(y.x) * WR0 + v2s(y.y) * WR1
                  + v2s(y.z) * WO0 + v2s(y.w) * WO1;
        t = __builtin_elementwise_max(t, Z);
        ushort hx = f2bf(t.x);
        ushort lx = f2bf(t.x - bf2f(hx));
        ushort hy = f2bf(t.y);
        ushort ly = f2bf(t.y - bf2f(hy));
        ushort2 hv2; hv2.x = hx; hv2.y = hy;
        ushort2 lv2; lv2.x = lx; lv2.y = ly;
        *reinterpret_cast<ushort2*>(h_hi + (size_t)wv * HIDDEN + c0) = hv2;
        *reinterpret_cast<ushort2*>(h_lo + (size_t)wv * HIDDEN + c0) = lv2;
    }
}

// ================= one-shot W2 split + transpose ============================
__global__ __launch_bounds__(256)
void k_splitw(const float* __restrict__ Wrel, const float* __restrict__ Wroot,
              ushort* __restrict__ wThi, ushort* __restrict__ wTlo) {
    int idx = blockIdx.x * 256 + threadIdx.x;   // 0..32767
    int k = idx >> 7;          // 0..255
    int n = idx & 127;
    float v = (k < 128) ? Wrel[(size_t)k * HIDDEN + n]
                        : Wroot[(size_t)(k - 128) * HIDDEN + n];
    ushort hb = f2bf(v);
    ushort lb = f2bf(v - bf2f(hb));
    wThi[(size_t)n * 256 + k] = hb;
    wTlo[(size_t)n * 256 + k] = lb;
}

// ============ layer-2 node update on the MATRIX pipe + layer-3 fusion =======
#define BM2 64
#define W3_STRIDE 7
#define XS_LD 40   // ushorts per LDS row: 32 k + 8 pad (80B, 16B-aligned)

__global__ __launch_bounds__(256)
void k_node2(const ushort* __restrict__ a_hi, const ushort* __restrict__ a_lo,
             const ushort* __restrict__ h_hi, const ushort* __restrict__ h_lo,
             const ushort* __restrict__ wThi, const ushort* __restrict__ wTlo,
             const float* __restrict__ b,
             const float* __restrict__ W3rel, const float* __restrict__ b3,
             const float* __restrict__ W3root,
             float* __restrict__ z, float* __restrict__ out, int N) {
    __shared__ __align__(16) ushort Xhi[BM2 * XS_LD];
    __shared__ __align__(16) ushort Xlo[BM2 * XS_LD];
    __shared__ __align__(16) ushort Whi[HIDDEN * XS_LD];
    __shared__ __align__(16) ushort Wlo[HIDDEN * XS_LD];
    __shared__ float W3s[HIDDEN * W3_STRIDE];

    const int tid  = threadIdx.x;
    const int lane = tid & 63;
    const int wid  = tid >> 6;
    const int ci   = lane & 15;
    const int kb   = lane >> 4;          // k-block 0..3
    const int nb   = blockIdx.x * BM2;

    if (tid < HIDDEN) {
#pragma unroll
        for (int c = 0; c < 3; ++c) {
            W3s[tid * W3_STRIDE + c]     = W3rel [tid * 3 + c];
            W3s[tid * W3_STRIDE + 3 + c] = W3root[tid * 3 + c];
        }
    }

    f32x4 acc[8];
#pragma unroll
    for (int tile = 0; tile < 8; ++tile) {
        float bb = b[tile * 16 + ci];
        f32x4 v; v[0] = bb; v[1] = bb; v[2] = bb; v[3] = bb;
        acc[tile] = v;
    }

    // staging index precompute
    const int sr  = tid >> 2;            // X row 0..63
    const int skq = (tid & 3) * 8;       // X k offset {0,8,16,24}

    // K = 256: 8 phases of 32. t<4: aggr; t>=4: h. W index linear in t.
    for (int t = 0; t < 8; ++t) {
        const ushort* Ahi = (t < 4) ? a_hi : h_hi;
        const ushort* Alo = (t < 4) ? a_lo : h_lo;
        const int kc = (t & 3) * 32;

        __syncthreads();                 // previous compute done before overwrite
        // stage X tile (pre-split bf16): 1 b128 per array per thread
        {
            int gr = nb + sr; if (gr >= N) gr = N - 1;
            size_t gofs = (size_t)gr * HIDDEN + kc + skq;
            *reinterpret_cast<short8*>(&Xhi[sr * XS_LD + skq]) =
                *reinterpret_cast<const short8*>(Ahi + gofs);
            *reinterpret_cast<short8*>(&Xlo[sr * XS_LD + skq]) =
                *reinterpret_cast<const short8*>(Alo + gofs);
        }
        // stage W tile: pure b128 copy from pre-split pre-transposed wT
#pragma unroll
        for (int q = 0; q < 2; ++q) {
            int idx = q * 256 + tid;     // 0..511
            int n  = idx >> 2;           // 0..127
            int kq = (idx & 3) * 8;      // 0,8,16,24
            size_t g = (size_t)n * 256 + t * 32 + kq;
            *reinterpret_cast<short8*>(&Whi[n * XS_LD + kq]) =
                *reinterpret_cast<const short8*>(wThi + g);
            *reinterpret_cast<short8*>(&Wlo[n * XS_LD + kq]) =
                *reinterpret_cast<const short8*>(wTlo + g);
        }
        __syncthreads();

        // A frags for this wave's 16-row tile (shared across all col tiles)
        int rl = wid * 16 + ci;
        short8 afh = *reinterpret_cast<const short8*>(&Xhi[rl * XS_LD + kb * 8]);
        short8 afl = *reinterpret_cast<const short8*>(&Xlo[rl * XS_LD + kb * 8]);
#pragma unroll
        for (int tile = 0; tile < 8; ++tile) {
            int nl = tile * 16 + ci;
            short8 bfh = *reinterpret_cast<const short8*>(&Whi[nl * XS_LD + kb * 8]);
            short8 bfl = *reinterpret_cast<const short8*>(&Wlo[nl * XS_LD + kb * 8]);
            acc[tile] = __builtin_amdgcn_mfma_f32_16x16x32_bf16(afh, bfh, acc[tile], 0, 0, 0);
            acc[tile] = __builtin_amdgcn_mfma_f32_16x16x32_bf16(afh, bfl, acc[tile], 0, 0, 0);
            acc[tile] = __builtin_amdgcn_mfma_f32_16x16x32_bf16(afl, bfh, acc[tile], 0, 0, 0);
        }
    }

    // epilogue: relu -> per-thread rank-8 partials vs LDS W3 -> width-16 shfl
    // D layout: row = kb*4 + m within wave tile, ch = tile*16 + ci
    const float b30 = b3[0], b31 = b3[1], b32 = b3[2];
#pragma unroll
    for (int m = 0; m < 4; ++m) {
        int node = nb + wid * 16 + kb * 4 + m;
        float zr0 = 0.f, zr1 = 0.f, zr2 = 0.f;
        float zo0 = 0.f, zo1 = 0.f, zo2 = 0.f;
#pragma unroll
        for (int tile = 0; tile < 8; ++tile) {
            float hv = fmaxf(acc[tile][m], 0.f);
            const float* w3 = &W3s[(tile * 16 + ci) * W3_STRIDE];
            zr0 = fmaf(hv, w3[0], zr0); zr1 = fmaf(hv, w3[1], zr1); zr2 = fmaf(hv, w3[2], zr2);
            zo0 = fmaf(hv, w3[3], zo0); zo1 = fmaf(hv, w3[4], zo1); zo2 = fmaf(hv, w3[5], zo2);
        }
#pragma unroll
        for (int d = 8; d >= 1; d >>= 1) {
            zr0 += __shfl_down(zr0, d, 16);
            zr1 += __shfl_down(zr1, d, 16);
            zr2 += __shfl_down(zr2, d, 16);
            zo0 += __shfl_down(zo0, d, 16);
            zo1 += __shfl_down(zo1, d, 16);
            zo2 += __shfl_down(zo2, d, 16);
        }
        if (ci == 0 && node < N) {
            z[(size_t)node * 3 + 0] = zr0;
            z[(size_t)node * 3 + 1] = zr1;
            z[(size_t)node * 3 + 2] = zr2;
            out[(size_t)node * 3 + 0] = zo0 + b30;
            out[(size_t)node * 3 + 1] = zo1 + b31;
            out[(size_t)node * 3 + 2] = zo2 + b32;
        }
    }
}

// ================= layer 3 gather =====================
__global__ __launch_bounds__(256)
void k_gather3(const int* __restrict__ offs, const int2* __restrict__ cpack,
               const float* __restrict__ z, float* __restrict__ out,
               int N, int E) {
    int i = blockIdx.x * 256 + threadIdx.x;
    if (i >= N) return;
    int start = offs[i], end = end_of(offs, i, N, E);
    float a0 = 0.f, a1 = 0.f, a2 = 0.f;
    for (int j = start; j < end; ++j) {
        int2  p = cpack[j];
        int   s = p.x;
        float w = __int_as_float(p.y);
        const float* zp = z + (size_t)s * 3;
        a0 = fmaf(w, zp[0], a0);
        a1 = fmaf(w, zp[1], a1);
        a2 = fmaf(w, zp[2], a2);
    }
    out[(size_t)i * 3 + 0] += a0;
    out[(size_t)i * 3 + 1] += a1;
    out[(size_t)i * 3 + 2] += a2;
}

extern "C" void kernel_launch(void* const* d_in, const int* in_sizes, int n_in,
                              void* d_out, int out_size, void* d_ws, size_t ws_size,
                              hipStream_t stream) {
    const float* x      = (const float*)d_in[0];
    const int*   ei     = (const int*)  d_in[1];
    const float* ew     = (const float*)d_in[2];
    const float* W1rel  = (const float*)d_in[4];
    const float* b1     = (const float*)d_in[5];
    const float* W1root = (const float*)d_in[6];
    const float* W2rel  = (const float*)d_in[7];
    const float* b2     = (const float*)d_in[8];
    const float* W2root = (const float*)d_in[9];
    const float* W3rel  = (const float*)d_in[10];
    const float* b3     = (const float*)d_in[11];
    const float* W3root = (const float*)d_in[12];
    float* out = (float*)d_out;

    const int N = in_sizes[0] / 2;
    const int E = in_sizes[2];
    const int* src = ei;
    const int* dst = ei + E;

    // -------- workspace layout (same total size as R15) --------
    ushort* h_hi = (ushort*)d_ws;
    ushort* h_lo = h_hi + (size_t)N * HIDDEN;
    ushort* a_hi = h_lo + (size_t)N * HIDDEN;
    ushort* a_lo = a_hi + (size_t)N * HIDDEN;
    int*   offs = (int*)(a_lo + (size_t)N * HIDDEN);
    int*   bsum = offs + N;
    size_t cpo  = (size_t)(bsum + SCAN_B - (int*)d_ws);
    cpo = (cpo + 1) & ~(size_t)1;          // 8B alignment
    int2*   cpack = (int2*)((int*)d_ws + cpo);
    size_t yvo  = (size_t)((char*)(cpack + E) - (char*)d_ws);
    yvo = (yvo + 15) & ~(size_t)15;        // 16B alignment
    float4* yv  = (float4*)((char*)d_ws + yvo);
    int* cnt  = (int*)cpack;               // alias: dead before k_fill writes cpack
    int* rank = (int*)d_ws;                // alias: dead before gatherfused writes h_hi
    float* z  = (float*)yv;                // alias: yv dead after gatherfused
    size_t wto = yvo + ((size_t)N * 3 * sizeof(float) + 15 & ~(size_t)15);
    wto = (wto + 15) & ~(size_t)15;
    ushort* wThi = (ushort*)((char*)d_ws + wto);          // 64KB
    ushort* wTlo = wThi + 128 * 256;                       // 64KB (within yv tail)

    const int nbScan = (N + SCAN_B - 1) / SCAN_B;

    // -------- CSR build --------
    hipMemsetAsync(cnt, 0, (size_t)N * sizeof(int), stream);
    k_hist <<<(E + 255) / 256, 256, 0, stream>>>(dst, cnt, rank, E);
    k_scan1<<<nbScan, SCAN_B, 0, stream>>>(cnt, offs, bsum, N);
    k_scan2<<<1, SCAN_B, 0, stream>>>(bsum, nbScan);
    k_scan3<<<nbScan, SCAN_B, 0, stream>>>(offs, bsum, N);
    k_fill <<<(E + 255) / 256, 256, 0, stream>>>(src, dst, ew, offs, rank, cpack, E);

    // -------- layer 1 aggregation (2ch) + y pack --------
    k_gather2<<<(N + 255) / 256, 256, 0, stream>>>(offs, cpack, x, yv, N, E);

    // -------- fused layer-2 aggregation + layer-1 node update (bf16 out) ----
    {
        long long threads = (long long)N * 64;
        k_gatherfused<<<(int)((threads + 255) / 256), 256, 0, stream>>>(
            offs, cpack, yv, W1rel, b1, W1root, h_hi, h_lo, a_hi, a_lo, N, E);
    }

    // -------- one-shot W2 split+transpose (yv dead now; writes its tail) ----
    k_splitw<<<128, 256, 0, stream>>>(W2rel, W2root, wThi, wTlo);

    // -------- MFMA layer-2 node update + layer-3 projection --------
    k_node2<<<(N + BM2 - 1) / BM2, 256, 0, stream>>>(
        a_hi, a_lo, h_hi, h_lo, wThi, wTlo, b2, W3rel, b3, W3root, z, out, N);

    // -------- layer 3 gather --------
    k_gather3<<<(N + 255) / 256, 256, 0, stream>>>(offs, cpack, z, out, N, E);
}